// Round 17
// baseline (213.216 us; speedup 1.0000x reference)
//
#include <hip/hip_runtime.h>

#define N_NODES 100000
#define E_EDGES 3200000
#define IN_CH 256
#define HID 32
#define OUT_CH 16

#define B_BUCKETS 250     // buckets over nodes
#define NPB 400           // nodes per bucket (250*400 = 100000 exactly)
#define CAP 20000         // LDS staging capacity in k_bsort
#define PB 256            // partition blocks
#define PCH (E_EDGES / PB)                  // 12500 exactly
#define GEMM_BLOCKS ((N_NODES + 63) / 64)   // 1563
#define AGG_BLOCKS 1600                     // bid%8<4 -> half A, >=4 -> half B

typedef unsigned short u16;
typedef __attribute__((ext_vector_type(8))) short bf16x8;
typedef __attribute__((ext_vector_type(4))) float f32x4;
typedef __attribute__((ext_vector_type(4))) unsigned u32x4;

__device__ __forceinline__ unsigned bf16rtn(float f) {
    unsigned u = __float_as_uint(f);
    return (u + 0x7FFFu + ((u >> 16) & 1u)) >> 16;   // round-to-nearest-even, finite inputs
}
__device__ __forceinline__ float bflo(unsigned u) { return __uint_as_float(u << 16); }
__device__ __forceinline__ float bfhi(unsigned u) { return __uint_as_float(u & 0xFFFF0000u); }

// ---------------- k_pre: hist (blocks 0..255, ghist rows) || MFMA gemm1 (blocks 256..) ----------------
// gemm writes SPLIT half-tables: h0A = channels 0..15, h0B = channels 16..31 (32B rows).

__global__ __launch_bounds__(256) void k_pre(const int* __restrict__ col,
                                             int* __restrict__ ghist,
                                             const float* __restrict__ W1,
                                             const float* __restrict__ x,
                                             u16* __restrict__ h0A, u16* __restrict__ h0B,
                                             int e, int n) {
    int bid = blockIdx.x;
    int tid = threadIdx.x;
    if (bid < PB) {
        __shared__ int h[B_BUCKETS];
        for (int i = tid; i < B_BUCKETS; i += 256) h[i] = 0;
        __syncthreads();
        int lo = bid * PCH, hi = lo + PCH;
        for (int i = lo + tid; i < hi; i += 256)
            atomicAdd(&h[col[i] / NPB], 1);
        __syncthreads();
        for (int i = tid; i < B_BUCKETS; i += 256)
            ghist[bid * B_BUCKETS + i] = h[i];           // coalesced row
    } else {
        int gbid = bid - PB;
        int lane = tid & 63;
        int wv = tid >> 6;
        int vbase = gbid * 64 + wv * 16;
        if (vbase >= n) return;             // N multiple of 16
        int arow = lane & 15;
        int kg = lane >> 4;
        const float* xr = x + (size_t)(vbase + arow) * IN_CH + kg * 8;

        // B-fragments straight from W1: elem j of (kt,ct) = W1[kt*32+(lane>>4)*8+j][ct*16+(lane&15)]
        uint4 bfrag[8][2];
        int colc0 = lane & 15;
        int krow0 = (lane >> 4) * 8;
#pragma unroll
        for (int kt = 0; kt < 8; ++kt) {
#pragma unroll
            for (int ct = 0; ct < 2; ++ct) {
                const float* wp = W1 + (size_t)(kt * 32 + krow0) * HID + ct * 16 + colc0;
                unsigned p[4];
#pragma unroll
                for (int pp = 0; pp < 4; ++pp) {
                    unsigned lo = bf16rtn(wp[(2 * pp) * HID]);
                    unsigned hi = bf16rtn(wp[(2 * pp + 1) * HID]);
                    p[pp] = lo | (hi << 16);
                }
                bfrag[kt][ct] = make_uint4(p[0], p[1], p[2], p[3]);
            }
        }

        f32x4 acc0 = {0.f, 0.f, 0.f, 0.f};
        f32x4 acc1 = {0.f, 0.f, 0.f, 0.f};
#pragma unroll
        for (int kt = 0; kt < 8; ++kt) {
            float4 a0 = *reinterpret_cast<const float4*>(xr + kt * 32);
            float4 a1 = *reinterpret_cast<const float4*>(xr + kt * 32 + 4);
            union { unsigned u[4]; bf16x8 v; } af;
            af.u[0] = bf16rtn(a0.x) | (bf16rtn(a0.y) << 16);
            af.u[1] = bf16rtn(a0.z) | (bf16rtn(a0.w) << 16);
            af.u[2] = bf16rtn(a1.x) | (bf16rtn(a1.y) << 16);
            af.u[3] = bf16rtn(a1.z) | (bf16rtn(a1.w) << 16);
            union { uint4 q; bf16x8 v; } b0, b1;
            b0.q = bfrag[kt][0];
            b1.q = bfrag[kt][1];
            acc0 = __builtin_amdgcn_mfma_f32_16x16x32_bf16(af.v, b0.v, acc0, 0, 0, 0);
            acc1 = __builtin_amdgcn_mfma_f32_16x16x32_bf16(af.v, b1.v, acc1, 0, 0, 0);
        }

        int r0 = (lane >> 4) * 4;
        int colo = lane & 15;
#pragma unroll
        for (int r = 0; r < 4; ++r) {
            int v = vbase + r0 + r;
            h0A[(size_t)v * 16 + colo] = (u16)bf16rtn(acc0[r]);   // unscaled; dis applied in k_bsort
            h0B[(size_t)v * 16 + colo] = (u16)bf16rtn(acc1[r]);
        }
    }
}

// ---------------- k_scan: per-bucket exclusive prefix over the 256 block counts ----------------

__global__ __launch_bounds__(256) void k_scan(int* __restrict__ ghist, int* __restrict__ bcnt) {
    __shared__ int a[256], b[256];
    int bu = blockIdx.x, t = threadIdx.x;
    int v = ghist[t * B_BUCKETS + bu];
    a[t] = v;
    __syncthreads();
    int* sp = a; int* dp = b;
    for (int off = 1; off < 256; off <<= 1) {
        dp[t] = sp[t] + ((t >= off) ? sp[t - off] : 0);
        __syncthreads();
        int* tm = sp; sp = dp; dp = tm;
    }
    ghist[t * B_BUCKETS + bu] = sp[t] - v;   // exclusive over blocks
    if (t == 255) bcnt[bu] = sp[t];
}

// ---------------- k_bscan: scan bucket totals -> bstart ----------------

__global__ void k_bscan(const int* __restrict__ bcnt, int* __restrict__ bstart) {
    __shared__ int a[256], b[256];
    int t = threadIdx.x;
    int myc = (t < B_BUCKETS) ? bcnt[t] : 0;
    a[t] = myc;
    __syncthreads();
    int* sp = a; int* dp = b;
    for (int off = 1; off < 256; off <<= 1) {
        dp[t] = sp[t] + ((t >= off) ? sp[t - off] : 0);
        __syncthreads();
        int* tm = sp; sp = dp; dp = tm;
    }
    int incl = sp[t];
    if (t < B_BUCKETS) bstart[t] = incl - myc;
    if (t == B_BUCKETS - 1) bstart[B_BUCKETS] = incl;
}

// ---------------- k_place: LDS-reorder partition, coalesced psrc writes, no global atomics ----------------

__global__ __launch_bounds__(256) void k_place(const int* __restrict__ row,
                                               const int* __restrict__ col,
                                               const int* __restrict__ bstart,
                                               const int* __restrict__ ghist,
                                               const int* __restrict__ bcnt,
                                               unsigned* __restrict__ psrc) {
    __shared__ unsigned stage[PCH];          // 50 KB
    __shared__ unsigned char bb[PCH];        // 12.5 KB
    __shared__ int base[B_BUCKETS];
    __shared__ int lstart[B_BUCKETS];
    __shared__ int cur[B_BUCKETS];
    __shared__ int sa[256], sb[256];
    int bid = blockIdx.x;
    int tid = threadIdx.x;

    int h = 0;
    if (tid < B_BUCKETS) {
        int e0 = ghist[bid * B_BUCKETS + tid];
        int e1 = (bid < PB - 1) ? ghist[(bid + 1) * B_BUCKETS + tid] : bcnt[tid];
        base[tid] = bstart[tid] + e0;
        h = e1 - e0;                         // this block's count for bucket tid
    }
    sa[tid] = h;
    __syncthreads();
    int* sp = sa; int* dp = sb;
    for (int off = 1; off < 256; off <<= 1) {
        dp[tid] = sp[tid] + ((tid >= off) ? sp[tid - off] : 0);
        __syncthreads();
        int* tm = sp; sp = dp; dp = tm;
    }
    int ex = sp[tid] - h;
    if (tid < B_BUCKETS) { lstart[tid] = ex; cur[tid] = ex; }
    __syncthreads();

    int lo = bid * PCH;
    for (int i = lo + tid; i < lo + PCH; i += 256) {
        int c = col[i];
        int b = c / NPB;
        int pos = atomicAdd(&cur[b], 1);
        stage[pos] = ((unsigned)(c - b * NPB) << 17) | (unsigned)row[i];
        bb[pos] = (unsigned char)b;
    }
    __syncthreads();

    for (int idx = tid; idx < PCH; idx += 256) {
        int b = bb[idx];
        psrc[base[b] + (idx - lstart[b])] = stage[idx];   // bucket runs in order -> coalesced
    }
}

// ---------------- k_bsort: bucket sort -> srow/deg/start/dis, then scale h0A/h0B ----------------

__global__ __launch_bounds__(512) void k_bsort(const unsigned* __restrict__ psrc,
                                               const int* __restrict__ bstart,
                                               int* __restrict__ srow, int* __restrict__ deg,
                                               int* __restrict__ start, float* __restrict__ dis,
                                               u16* __restrict__ h0A, u16* __restrict__ h0B) {
    __shared__ unsigned buf[CAP];
    __shared__ int cnt[512];
    __shared__ int sa[512];
    __shared__ int sb[512];
    int b = blockIdx.x, t = threadIdx.x;
    int s0 = bstart[b], s1 = bstart[b + 1], len = s1 - s0;

    cnt[t] = 0;
    __syncthreads();
    for (int i = t; i < len; i += 512)
        atomicAdd(&cnt[psrc[s0 + i] >> 17], 1);
    __syncthreads();

    sa[t] = cnt[t];
    __syncthreads();
    int* sp = sa; int* dp = sb;
    for (int off = 1; off < 512; off <<= 1) {
        dp[t] = sp[t] + ((t >= off) ? sp[t - off] : 0);
        __syncthreads();
        int* tm = sp; sp = dp; dp = tm;
    }
    int ex = sp[t] - cnt[t];
    __syncthreads();
    sa[t] = ex;
    sb[t] = ex;
    float dvv = 0.f;
    if (t < NPB) {
        int node = b * NPB + t;
        int d = cnt[t];
        deg[node] = d;
        start[node] = s0 + ex;
        dvv = rsqrtf((float)(d + 1));
        dis[node] = dvv;
    }
    __syncthreads();

    bool fits = (len <= CAP);
    for (int i = t; i < len; i += 512) {
        unsigned p = psrc[s0 + i];
        int cl = (int)(p >> 17);
        int pos = atomicAdd(&sb[cl], 1);
        if (fits) buf[pos] = p & 0x1FFFFu;
        else      srow[s0 + pos] = (int)(p & 0x1FFFFu);
    }
    __syncthreads();
    if (fits)
        for (int i = t; i < len; i += 512)
            srow[s0 + i] = (int)buf[i];

    // scale phase: h0A/h0B rows *= dis (in place; block owns its 400 nodes exclusively)
    if (t < NPB) {
        int node = b * NPB + t;
        uint4* pA = reinterpret_cast<uint4*>(h0A + (size_t)node * 16);
        uint4* pB = reinterpret_cast<uint4*>(h0B + (size_t)node * 16);
#pragma unroll
        for (int half = 0; half < 2; ++half) {
            uint4* p4 = half ? pB : pA;
#pragma unroll
            for (int qq = 0; qq < 2; ++qq) {
                uint4 pv = p4[qq];
                unsigned r[4];
                unsigned comp[4] = {pv.x, pv.y, pv.z, pv.w};
#pragma unroll
                for (int k = 0; k < 4; ++k) {
                    float lo = bflo(comp[k]) * dvv;
                    float hi = bfhi(comp[k]) * dvv;
                    r[k] = bf16rtn(lo) | (bf16rtn(hi) << 16);
                }
                p4[qq] = make_uint4(r[0], r[1], r[2], r[3]);
            }
        }
    }
}

// 8 FMAs of one gathered uint4 (8 bf16) into acc[8]
#define ACC8(gv)                                   \
    acc[0] += bflo(gv.x); acc[1] += bfhi(gv.x);    \
    acc[2] += bflo(gv.y); acc[3] += bfhi(gv.y);    \
    acc[4] += bflo(gv.z); acc[5] += bfhi(gv.z);    \
    acc[6] += bflo(gv.w); acc[7] += bfhi(gv.w);

// ---------------- aggregation 1 (half-split): hs_half = bf16(dis*relu(dv*(sum+self)+b1_half)) ----------------
// Half chosen by bid%8 (<4 -> A, >=4 -> B): XCD round-robin keeps each XCD's gather table 3.2MB.
// 32 dests/wave, 2 lanes/dest, lane covers 8 channels (16B) of 32B rows.

__global__ __launch_bounds__(256, 6) void k_agg1(const u16* __restrict__ h0A,
                                                 const u16* __restrict__ h0B,
                                                 const int* __restrict__ srow,
                                                 const int* __restrict__ start,
                                                 const int* __restrict__ deg,
                                                 const float* __restrict__ dis,
                                                 const float* __restrict__ b1,
                                                 u16* __restrict__ hsA,
                                                 u16* __restrict__ hsB, int n) {
    int bid = blockIdx.x;
    int m8 = bid & 7;
    int half = (m8 >= 4);
    int gblk = (bid >> 3) * 4 + (m8 & 3);
    const u16* tab = half ? h0B : h0A;
    u16* outt = half ? hsB : hsA;
    int co = half * 16;

    int tid = threadIdx.x;
    int lane = tid & 63;
    int g = lane >> 1;          // dest within wave, 0..31
    int hq = lane & 1;          // 8-channel octet within half
    int wv = tid >> 6;
    int v = gblk * 128 + wv * 32 + g;
    if (v >= n) v = n - 1;
    int s = start[v], d = deg[v];
    float dv = dis[v];

    float acc[8];
#pragma unroll
    for (int c = 0; c < 8; ++c) acc[c] = 0.f;

    int i = 0;
    for (; i + 8 <= d; i += 8) {
        int u0 = srow[s + i + 0], u1 = srow[s + i + 1], u2 = srow[s + i + 2], u3 = srow[s + i + 3];
        int u4 = srow[s + i + 4], u5 = srow[s + i + 5], u6 = srow[s + i + 6], u7 = srow[s + i + 7];
        uint4 g0 = *reinterpret_cast<const uint4*>(tab + (size_t)u0 * 16 + hq * 8);
        uint4 g1 = *reinterpret_cast<const uint4*>(tab + (size_t)u1 * 16 + hq * 8);
        uint4 g2 = *reinterpret_cast<const uint4*>(tab + (size_t)u2 * 16 + hq * 8);
        uint4 g3 = *reinterpret_cast<const uint4*>(tab + (size_t)u3 * 16 + hq * 8);
        uint4 g4 = *reinterpret_cast<const uint4*>(tab + (size_t)u4 * 16 + hq * 8);
        uint4 g5 = *reinterpret_cast<const uint4*>(tab + (size_t)u5 * 16 + hq * 8);
        uint4 g6 = *reinterpret_cast<const uint4*>(tab + (size_t)u6 * 16 + hq * 8);
        uint4 g7 = *reinterpret_cast<const uint4*>(tab + (size_t)u7 * 16 + hq * 8);
        ACC8(g0) ACC8(g1) ACC8(g2) ACC8(g3) ACC8(g4) ACC8(g5) ACC8(g6) ACC8(g7)
    }
    for (; i < d; ++i) {
        int u = srow[s + i];
        uint4 gv = *reinterpret_cast<const uint4*>(tab + (size_t)u * 16 + hq * 8);
        ACC8(gv)
    }

    uint4 sv = *reinterpret_cast<const uint4*>(tab + (size_t)v * 16 + hq * 8);
    float self[8] = {bflo(sv.x), bfhi(sv.x), bflo(sv.y), bfhi(sv.y),
                     bflo(sv.z), bfhi(sv.z), bflo(sv.w), bfhi(sv.w)};
    float4 ba = *reinterpret_cast<const float4*>(b1 + co + hq * 8);
    float4 bb = *reinterpret_cast<const float4*>(b1 + co + hq * 8 + 4);
    float bias[8] = {ba.x, ba.y, ba.z, ba.w, bb.x, bb.y, bb.z, bb.w};

    unsigned pk[4];
#pragma unroll
    for (int p = 0; p < 4; ++p) {
        float o0 = dv * fmaxf(0.f, fmaf(dv, acc[2 * p] + self[2 * p], bias[2 * p]));
        float o1 = dv * fmaxf(0.f, fmaf(dv, acc[2 * p + 1] + self[2 * p + 1], bias[2 * p + 1]));
        pk[p] = bf16rtn(o0) | (bf16rtn(o1) << 16);
    }
    u32x4 pkv = {pk[0], pk[1], pk[2], pk[3]};
    __builtin_nontemporal_store(pkv, reinterpret_cast<u32x4*>(outt + (size_t)v * 16 + hq * 8));
}

// ---------------- aggregation 2 (half-split): sf_half = dv*(sum hs_u + hs_v)  (f32) ----------------

__global__ __launch_bounds__(256, 6) void k_agg2(const u16* __restrict__ hsA,
                                                 const u16* __restrict__ hsB,
                                                 const int* __restrict__ srow,
                                                 const int* __restrict__ start,
                                                 const int* __restrict__ deg,
                                                 const float* __restrict__ dis,
                                                 float* __restrict__ sfA,
                                                 float* __restrict__ sfB, int n) {
    int bid = blockIdx.x;
    int m8 = bid & 7;
    int half = (m8 >= 4);
    int gblk = (bid >> 3) * 4 + (m8 & 3);
    const u16* tab = half ? hsB : hsA;
    float* outt = half ? sfB : sfA;

    int tid = threadIdx.x;
    int lane = tid & 63;
    int g = lane >> 1;
    int hq = lane & 1;
    int wv = tid >> 6;
    int v = gblk * 128 + wv * 32 + g;
    if (v >= n) v = n - 1;
    int s = start[v], d = deg[v];
    float dv = dis[v];

    float acc[8];
#pragma unroll
    for (int c = 0; c < 8; ++c) acc[c] = 0.f;

    int i = 0;
    for (; i + 8 <= d; i += 8) {
        int u0 = srow[s + i + 0], u1 = srow[s + i + 1], u2 = srow[s + i + 2], u3 = srow[s + i + 3];
        int u4 = srow[s + i + 4], u5 = srow[s + i + 5], u6 = srow[s + i + 6], u7 = srow[s + i + 7];
        uint4 g0 = *reinterpret_cast<const uint4*>(tab + (size_t)u0 * 16 + hq * 8);
        uint4 g1 = *reinterpret_cast<const uint4*>(tab + (size_t)u1 * 16 + hq * 8);
        uint4 g2 = *reinterpret_cast<const uint4*>(tab + (size_t)u2 * 16 + hq * 8);
        uint4 g3 = *reinterpret_cast<const uint4*>(tab + (size_t)u3 * 16 + hq * 8);
        uint4 g4 = *reinterpret_cast<const uint4*>(tab + (size_t)u4 * 16 + hq * 8);
        uint4 g5 = *reinterpret_cast<const uint4*>(tab + (size_t)u5 * 16 + hq * 8);
        uint4 g6 = *reinterpret_cast<const uint4*>(tab + (size_t)u6 * 16 + hq * 8);
        uint4 g7 = *reinterpret_cast<const uint4*>(tab + (size_t)u7 * 16 + hq * 8);
        ACC8(g0) ACC8(g1) ACC8(g2) ACC8(g3) ACC8(g4) ACC8(g5) ACC8(g6) ACC8(g7)
    }
    for (; i < d; ++i) {
        int u = srow[s + i];
        uint4 gv = *reinterpret_cast<const uint4*>(tab + (size_t)u * 16 + hq * 8);
        ACC8(gv)
    }

    uint4 sv4 = *reinterpret_cast<const uint4*>(tab + (size_t)v * 16 + hq * 8);
    float self[8] = {bflo(sv4.x), bfhi(sv4.x), bflo(sv4.y), bfhi(sv4.y),
                     bflo(sv4.z), bfhi(sv4.z), bflo(sv4.w), bfhi(sv4.w)};
    float* dst = outt + (size_t)v * 16 + hq * 8;
    f32x4 o0 = {dv * (acc[0] + self[0]), dv * (acc[1] + self[1]),
                dv * (acc[2] + self[2]), dv * (acc[3] + self[3])};
    f32x4 o1 = {dv * (acc[4] + self[4]), dv * (acc[5] + self[5]),
                dv * (acc[6] + self[6]), dv * (acc[7] + self[7])};
    __builtin_nontemporal_store(o0, reinterpret_cast<f32x4*>(dst));
    __builtin_nontemporal_store(o1, reinterpret_cast<f32x4*>(dst + 4));
}

// ---------------- output transform: out = [sfA|sfB] @ [Wmu|Wlv] + bias ----------------

__global__ __launch_bounds__(256) void k_out(const float* __restrict__ sfA,
                                             const float* __restrict__ sfB,
                                             const float* __restrict__ Wmu,
                                             const float* __restrict__ Wlv,
                                             const float* __restrict__ bmu,
                                             const float* __restrict__ blv,
                                             float* __restrict__ out, int n) {
    __shared__ float wc[32][33];
    __shared__ float sbuf[8][33];
    int tid = threadIdx.x;
    for (int i = tid; i < 32 * 32; i += 256) {
        int k = i >> 5, c = i & 31;
        wc[k][c] = (c < OUT_CH) ? Wmu[k * OUT_CH + c] : Wlv[k * OUT_CH + (c - OUT_CH)];
    }
    int vbase = blockIdx.x * 8;
    {
        int gg = tid >> 5, kk = tid & 31;
        int vsrc = vbase + gg; if (vsrc >= n) vsrc = n - 1;
        sbuf[gg][kk] = (kk < 16) ? sfA[(size_t)vsrc * 16 + kk]
                                 : sfB[(size_t)vsrc * 16 + (kk - 16)];
    }
    __syncthreads();

    int g = tid >> 5, c = tid & 31;
    int v = vbase + g;
    if (v >= n) return;
    float o = 0.f;
#pragma unroll
    for (int k = 0; k < 32; ++k)
        o = fmaf(sbuf[g][k], wc[k][c], o);
    if (c < OUT_CH)
        out[(size_t)v * OUT_CH + c] = o + bmu[c];
    else
        out[(size_t)N_NODES * OUT_CH + (size_t)v * OUT_CH + (c - OUT_CH)] = o + blv[c - OUT_CH];
}

// ---------------- launch ----------------

extern "C" void kernel_launch(void* const* d_in, const int* in_sizes, int n_in,
                              void* d_out, int out_size, void* d_ws, size_t ws_size,
                              hipStream_t stream) {
    const float* x   = (const float*)d_in[0];
    const int*   ei  = (const int*)d_in[1];
    const float* W1  = (const float*)d_in[2];
    const float* b1  = (const float*)d_in[3];
    const float* Wmu = (const float*)d_in[4];
    const float* bmu = (const float*)d_in[5];
    const float* Wlv = (const float*)d_in[6];
    const float* blv = (const float*)d_in[7];
    float* out = (float*)d_out;

    const int* row = ei;            // edge_index[0]
    const int* col = ei + E_EDGES;  // edge_index[1]

    char* w = (char*)d_ws;
    int*   bcnt   = (int*)w;  w += 1024;
    int*   bstart = (int*)w;  w += 1024;
    int*   ghist  = (int*)w;  w += (size_t)PB * B_BUCKETS * 4;   // 256 KB
    int*   deg    = (int*)w;  w += (size_t)N_NODES * 4;
    float* dis    = (float*)w; w += (size_t)N_NODES * 4;
    int*   start  = (int*)w;  w += (size_t)N_NODES * 4;
    int*   srow   = (int*)w;  w += (size_t)E_EDGES * 4;
    u16*   h0A    = (u16*)w;  w += (size_t)N_NODES * 16 * 2;
    u16*   h0B    = (u16*)w;  w += (size_t)N_NODES * 16 * 2;
    u16*   hsA    = (u16*)w;  w += (size_t)N_NODES * 16 * 2;
    u16*   hsB    = (u16*)w;  w += (size_t)N_NODES * 16 * 2;
    float* sfA    = (float*)w; w += (size_t)N_NODES * 16 * 4;
    float* sfB    = (float*)w; w += (size_t)N_NODES * 16 * 4;
    unsigned* psrc = (unsigned*)w; w += (size_t)E_EDGES * 4;

    const int TB = 256;
    k_pre<<<PB + GEMM_BLOCKS, TB, 0, stream>>>(col, ghist, W1, x, h0A, h0B, E_EDGES, N_NODES);
    k_scan<<<B_BUCKETS, 256, 0, stream>>>(ghist, bcnt);
    k_bscan<<<1, 256, 0, stream>>>(bcnt, bstart);
    k_place<<<PB, TB, 0, stream>>>(row, col, bstart, ghist, bcnt, psrc);
    k_bsort<<<B_BUCKETS, 512, 0, stream>>>(psrc, bstart, srow, deg, start, dis, h0A, h0B);
    k_agg1<<<AGG_BLOCKS, TB, 0, stream>>>(h0A, h0B, srow, start, deg, dis, b1, hsA, hsB, N_NODES);
    k_agg2<<<AGG_BLOCKS, TB, 0, stream>>>(hsA, hsB, srow, start, deg, dis, sfA, sfB, N_NODES);
    k_out<<<(N_NODES + 7) / 8, TB, 0, stream>>>(sfA, sfB, Wmu, Wlv, bmu, blv, out, N_NODES);
}

// Round 18
// 183.501 us; speedup vs baseline: 1.1619x; 1.1619x over previous
//
#include <hip/hip_runtime.h>

#define N_NODES 100000
#define E_EDGES 3200000
#define IN_CH 256
#define HID 32
#define OUT_CH 16

#define B_BUCKETS 250     // buckets over nodes
#define NPB 400           // nodes per bucket (250*400 = 100000 exactly)
#define CAP 20000         // LDS staging capacity in k_bsort
#define PB 256            // partition blocks
#define PCH (E_EDGES / PB)                  // 12500 exactly
#define GEMM_BLOCKS ((N_NODES + 63) / 64)   // 1563

typedef unsigned short u16;
typedef __attribute__((ext_vector_type(8))) short bf16x8;
typedef __attribute__((ext_vector_type(4))) float f32x4;

__device__ __forceinline__ unsigned bf16rtn(float f) {
    unsigned u = __float_as_uint(f);
    return (u + 0x7FFFu + ((u >> 16) & 1u)) >> 16;   // round-to-nearest-even, finite inputs
}
__device__ __forceinline__ float bflo(unsigned u) { return __uint_as_float(u << 16); }
__device__ __forceinline__ float bfhi(unsigned u) { return __uint_as_float(u & 0xFFFF0000u); }

// ---------------- k_pre: hist (blocks 0..255, ghist rows) || MFMA gemm1 (blocks 256..) ----------------

__global__ __launch_bounds__(256) void k_pre(const int* __restrict__ col,
                                             int* __restrict__ ghist,
                                             const float* __restrict__ W1,
                                             const float* __restrict__ x,
                                             u16* __restrict__ h0sh, int e, int n) {
    int bid = blockIdx.x;
    int tid = threadIdx.x;
    if (bid < PB) {
        __shared__ int h[B_BUCKETS];
        for (int i = tid; i < B_BUCKETS; i += 256) h[i] = 0;
        __syncthreads();
        int lo = bid * PCH, hi = lo + PCH;
        for (int i = lo + tid; i < hi; i += 256)
            atomicAdd(&h[col[i] / NPB], 1);
        __syncthreads();
        for (int i = tid; i < B_BUCKETS; i += 256)
            ghist[bid * B_BUCKETS + i] = h[i];           // coalesced row
    } else {
        int gbid = bid - PB;
        int lane = tid & 63;
        int wv = tid >> 6;
        int vbase = gbid * 64 + wv * 16;
        if (vbase >= n) return;             // N multiple of 16
        int arow = lane & 15;
        int kg = lane >> 4;
        const float* xr = x + (size_t)(vbase + arow) * IN_CH + kg * 8;

        // B-fragments straight from W1: elem j of (kt,ct) = W1[kt*32+(lane>>4)*8+j][ct*16+(lane&15)]
        uint4 bfrag[8][2];
        int colc0 = lane & 15;
        int krow0 = (lane >> 4) * 8;
#pragma unroll
        for (int kt = 0; kt < 8; ++kt) {
#pragma unroll
            for (int ct = 0; ct < 2; ++ct) {
                const float* wp = W1 + (size_t)(kt * 32 + krow0) * HID + ct * 16 + colc0;
                unsigned p[4];
#pragma unroll
                for (int pp = 0; pp < 4; ++pp) {
                    unsigned lo = bf16rtn(wp[(2 * pp) * HID]);
                    unsigned hi = bf16rtn(wp[(2 * pp + 1) * HID]);
                    p[pp] = lo | (hi << 16);
                }
                bfrag[kt][ct] = make_uint4(p[0], p[1], p[2], p[3]);
            }
        }

        f32x4 acc0 = {0.f, 0.f, 0.f, 0.f};
        f32x4 acc1 = {0.f, 0.f, 0.f, 0.f};
#pragma unroll
        for (int kt = 0; kt < 8; ++kt) {
            float4 a0 = *reinterpret_cast<const float4*>(xr + kt * 32);
            float4 a1 = *reinterpret_cast<const float4*>(xr + kt * 32 + 4);
            union { unsigned u[4]; bf16x8 v; } af;
            af.u[0] = bf16rtn(a0.x) | (bf16rtn(a0.y) << 16);
            af.u[1] = bf16rtn(a0.z) | (bf16rtn(a0.w) << 16);
            af.u[2] = bf16rtn(a1.x) | (bf16rtn(a1.y) << 16);
            af.u[3] = bf16rtn(a1.z) | (bf16rtn(a1.w) << 16);
            union { uint4 q; bf16x8 v; } b0, b1;
            b0.q = bfrag[kt][0];
            b1.q = bfrag[kt][1];
            acc0 = __builtin_amdgcn_mfma_f32_16x16x32_bf16(af.v, b0.v, acc0, 0, 0, 0);
            acc1 = __builtin_amdgcn_mfma_f32_16x16x32_bf16(af.v, b1.v, acc1, 0, 0, 0);
        }

        int r0 = (lane >> 4) * 4;
        int colo = lane & 15;
#pragma unroll
        for (int r = 0; r < 4; ++r) {
            int v = vbase + r0 + r;
            h0sh[(size_t)v * HID + colo]      = (u16)bf16rtn(acc0[r]);   // unscaled; dis applied in k_bsort
            h0sh[(size_t)v * HID + 16 + colo] = (u16)bf16rtn(acc1[r]);
        }
    }
}

// ---------------- k_scan: per-bucket exclusive prefix over the 256 block counts ----------------

__global__ __launch_bounds__(256) void k_scan(int* __restrict__ ghist, int* __restrict__ bcnt) {
    __shared__ int a[256], b[256];
    int bu = blockIdx.x, t = threadIdx.x;
    int v = ghist[t * B_BUCKETS + bu];
    a[t] = v;
    __syncthreads();
    int* sp = a; int* dp = b;
    for (int off = 1; off < 256; off <<= 1) {
        dp[t] = sp[t] + ((t >= off) ? sp[t - off] : 0);
        __syncthreads();
        int* tm = sp; sp = dp; dp = tm;
    }
    ghist[t * B_BUCKETS + bu] = sp[t] - v;   // exclusive over blocks
    if (t == 255) bcnt[bu] = sp[t];
}

// ---------------- k_bscan: scan bucket totals -> bstart ----------------

__global__ void k_bscan(const int* __restrict__ bcnt, int* __restrict__ bstart) {
    __shared__ int a[256], b[256];
    int t = threadIdx.x;
    int myc = (t < B_BUCKETS) ? bcnt[t] : 0;
    a[t] = myc;
    __syncthreads();
    int* sp = a; int* dp = b;
    for (int off = 1; off < 256; off <<= 1) {
        dp[t] = sp[t] + ((t >= off) ? sp[t - off] : 0);
        __syncthreads();
        int* tm = sp; sp = dp; dp = tm;
    }
    int incl = sp[t];
    if (t < B_BUCKETS) bstart[t] = incl - myc;
    if (t == B_BUCKETS - 1) bstart[B_BUCKETS] = incl;
}

// ---------------- k_place: LDS-reorder partition, coalesced psrc writes, no global atomics ----------------

__global__ __launch_bounds__(256) void k_place(const int* __restrict__ row,
                                               const int* __restrict__ col,
                                               const int* __restrict__ bstart,
                                               const int* __restrict__ ghist,
                                               const int* __restrict__ bcnt,
                                               unsigned* __restrict__ psrc) {
    __shared__ unsigned stage[PCH];          // 50 KB
    __shared__ unsigned char bb[PCH];        // 12.5 KB
    __shared__ int base[B_BUCKETS];
    __shared__ int lstart[B_BUCKETS];
    __shared__ int cur[B_BUCKETS];
    __shared__ int sa[256], sb[256];
    int bid = blockIdx.x;
    int tid = threadIdx.x;

    int h = 0;
    if (tid < B_BUCKETS) {
        int e0 = ghist[bid * B_BUCKETS + tid];
        int e1 = (bid < PB - 1) ? ghist[(bid + 1) * B_BUCKETS + tid] : bcnt[tid];
        base[tid] = bstart[tid] + e0;
        h = e1 - e0;                         // this block's count for bucket tid
    }
    sa[tid] = h;
    __syncthreads();
    int* sp = sa; int* dp = sb;
    for (int off = 1; off < 256; off <<= 1) {
        dp[tid] = sp[tid] + ((tid >= off) ? sp[tid - off] : 0);
        __syncthreads();
        int* tm = sp; sp = dp; dp = tm;
    }
    int ex = sp[tid] - h;
    if (tid < B_BUCKETS) { lstart[tid] = ex; cur[tid] = ex; }
    __syncthreads();

    int lo = bid * PCH;
    for (int i = lo + tid; i < lo + PCH; i += 256) {
        int c = col[i];
        int b = c / NPB;
        int pos = atomicAdd(&cur[b], 1);
        stage[pos] = ((unsigned)(c - b * NPB) << 17) | (unsigned)row[i];
        bb[pos] = (unsigned char)b;
    }
    __syncthreads();

    for (int idx = tid; idx < PCH; idx += 256) {
        int b = bb[idx];
        psrc[base[b] + (idx - lstart[b])] = stage[idx];   // bucket runs in order -> coalesced
    }
}

// ---------------- k_bsort: bucket sort -> srow/deg/start/dis, then scale h0sh ----------------

__global__ __launch_bounds__(512) void k_bsort(const unsigned* __restrict__ psrc,
                                               const int* __restrict__ bstart,
                                               int* __restrict__ srow, int* __restrict__ deg,
                                               int* __restrict__ start, float* __restrict__ dis,
                                               u16* __restrict__ h0sh) {
    __shared__ unsigned buf[CAP];
    __shared__ int cnt[512];
    __shared__ int sa[512];
    __shared__ int sb[512];
    int b = blockIdx.x, t = threadIdx.x;
    int s0 = bstart[b], s1 = bstart[b + 1], len = s1 - s0;

    cnt[t] = 0;
    __syncthreads();
    for (int i = t; i < len; i += 512)
        atomicAdd(&cnt[psrc[s0 + i] >> 17], 1);
    __syncthreads();

    sa[t] = cnt[t];
    __syncthreads();
    int* sp = sa; int* dp = sb;
    for (int off = 1; off < 512; off <<= 1) {
        dp[t] = sp[t] + ((t >= off) ? sp[t - off] : 0);
        __syncthreads();
        int* tm = sp; sp = dp; dp = tm;
    }
    int ex = sp[t] - cnt[t];
    __syncthreads();
    sa[t] = ex;
    sb[t] = ex;
    float dvv = 0.f;
    if (t < NPB) {
        int node = b * NPB + t;
        int d = cnt[t];
        deg[node] = d;
        start[node] = s0 + ex;
        dvv = rsqrtf((float)(d + 1));
        dis[node] = dvv;
    }
    __syncthreads();

    bool fits = (len <= CAP);
    for (int i = t; i < len; i += 512) {
        unsigned p = psrc[s0 + i];
        int cl = (int)(p >> 17);
        int pos = atomicAdd(&sb[cl], 1);
        if (fits) buf[pos] = p & 0x1FFFFu;
        else      srow[s0 + pos] = (int)(p & 0x1FFFFu);
    }
    __syncthreads();
    if (fits)
        for (int i = t; i < len; i += 512)
            srow[s0 + i] = (int)buf[i];

    // scale phase: h0sh[v] *= dis[v] (in place; block owns its 400 nodes exclusively)
    if (t < NPB) {
        int node = b * NPB + t;
        uint4* p4 = reinterpret_cast<uint4*>(h0sh + (size_t)node * HID);
#pragma unroll
        for (int qq = 0; qq < 4; ++qq) {
            uint4 pv = p4[qq];
            unsigned r[4];
            unsigned comp[4] = {pv.x, pv.y, pv.z, pv.w};
#pragma unroll
            for (int k = 0; k < 4; ++k) {
                float lo = bflo(comp[k]) * dvv;
                float hi = bfhi(comp[k]) * dvv;
                r[k] = bf16rtn(lo) | (bf16rtn(hi) << 16);
            }
            p4[qq] = make_uint4(r[0], r[1], r[2], r[3]);
        }
    }
}

// 8 FMAs of one gathered uint4 (8 bf16) into acc[8]
#define ACC8(gv)                                   \
    acc[0] += bflo(gv.x); acc[1] += bfhi(gv.x);    \
    acc[2] += bflo(gv.y); acc[3] += bfhi(gv.y);    \
    acc[4] += bflo(gv.z); acc[5] += bfhi(gv.z);    \
    acc[6] += bflo(gv.w); acc[7] += bfhi(gv.w);

// ---------------- aggregation 1: hsh = bf16( dis * relu(dv*(sum h0s_u + h0s_v) + b1) ) ----------------
// 16 dests/wave, 4 lanes/dest, lane covers 8 channels (16B gather), batch-8 named scalars.

__global__ __launch_bounds__(256, 6) void k_agg1(const u16* __restrict__ h0sh,
                                                 const int* __restrict__ srow,
                                                 const int* __restrict__ start,
                                                 const int* __restrict__ deg,
                                                 const float* __restrict__ dis,
                                                 const float* __restrict__ b1,
                                                 u16* __restrict__ hsh, int n) {
    int tid = threadIdx.x;
    int lane = tid & 63;
    int g = lane >> 2;          // dest within wave, 0..15
    int q = lane & 3;           // channel-octet, 0..3
    int wv = tid >> 6;
    int v = blockIdx.x * 64 + wv * 16 + g;
    if (v >= n) v = n - 1;
    int s = start[v], d = deg[v];
    float dv = dis[v];

    float acc[8];
#pragma unroll
    for (int c = 0; c < 8; ++c) acc[c] = 0.f;

    int i = 0;
    for (; i + 8 <= d; i += 8) {
        int u0 = srow[s + i + 0], u1 = srow[s + i + 1], u2 = srow[s + i + 2], u3 = srow[s + i + 3];
        int u4 = srow[s + i + 4], u5 = srow[s + i + 5], u6 = srow[s + i + 6], u7 = srow[s + i + 7];
        uint4 g0 = *reinterpret_cast<const uint4*>(h0sh + (size_t)u0 * HID + q * 8);
        uint4 g1 = *reinterpret_cast<const uint4*>(h0sh + (size_t)u1 * HID + q * 8);
        uint4 g2 = *reinterpret_cast<const uint4*>(h0sh + (size_t)u2 * HID + q * 8);
        uint4 g3 = *reinterpret_cast<const uint4*>(h0sh + (size_t)u3 * HID + q * 8);
        uint4 g4 = *reinterpret_cast<const uint4*>(h0sh + (size_t)u4 * HID + q * 8);
        uint4 g5 = *reinterpret_cast<const uint4*>(h0sh + (size_t)u5 * HID + q * 8);
        uint4 g6 = *reinterpret_cast<const uint4*>(h0sh + (size_t)u6 * HID + q * 8);
        uint4 g7 = *reinterpret_cast<const uint4*>(h0sh + (size_t)u7 * HID + q * 8);
        ACC8(g0) ACC8(g1) ACC8(g2) ACC8(g3) ACC8(g4) ACC8(g5) ACC8(g6) ACC8(g7)
    }
    for (; i < d; ++i) {
        int u = srow[s + i];
        uint4 gv = *reinterpret_cast<const uint4*>(h0sh + (size_t)u * HID + q * 8);
        ACC8(gv)
    }

    uint4 sv = *reinterpret_cast<const uint4*>(h0sh + (size_t)v * HID + q * 8);
    float self[8] = {bflo(sv.x), bfhi(sv.x), bflo(sv.y), bfhi(sv.y),
                     bflo(sv.z), bfhi(sv.z), bflo(sv.w), bfhi(sv.w)};
    float4 ba = *reinterpret_cast<const float4*>(b1 + q * 8);
    float4 bb = *reinterpret_cast<const float4*>(b1 + q * 8 + 4);
    float bias[8] = {ba.x, ba.y, ba.z, ba.w, bb.x, bb.y, bb.z, bb.w};

    unsigned pk[4];
#pragma unroll
    for (int p = 0; p < 4; ++p) {
        float o0 = dv * fmaxf(0.f, fmaf(dv, acc[2 * p] + self[2 * p], bias[2 * p]));
        float o1 = dv * fmaxf(0.f, fmaf(dv, acc[2 * p + 1] + self[2 * p + 1], bias[2 * p + 1]));
        pk[p] = bf16rtn(o0) | (bf16rtn(o1) << 16);
    }
    *reinterpret_cast<uint4*>(hsh + (size_t)v * HID + q * 8) = make_uint4(pk[0], pk[1], pk[2], pk[3]);
}

// ---------------- aggregation 2 + FUSED output transform ----------------
// Gather phase identical to agg1; epilogue: svec in LDS, out = svec @ [Wmu|Wlv] + bias.

__global__ __launch_bounds__(256, 6) void k_agg2(const u16* __restrict__ hsh,
                                                 const int* __restrict__ srow,
                                                 const int* __restrict__ start,
                                                 const int* __restrict__ deg,
                                                 const float* __restrict__ dis,
                                                 const float* __restrict__ Wmu,
                                                 const float* __restrict__ Wlv,
                                                 const float* __restrict__ bmu,
                                                 const float* __restrict__ blv,
                                                 float* __restrict__ out, int n) {
    __shared__ float wc[32][33];       // [Wmu | Wlv]
    __shared__ float svec[64][33];     // per-block aggregated s vectors (64 dests)
    int tid = threadIdx.x;
    for (int i = tid; i < 32 * 32; i += 256) {
        int k = i >> 5, c = i & 31;
        wc[k][c] = (c < OUT_CH) ? Wmu[k * OUT_CH + c] : Wlv[k * OUT_CH + (c - OUT_CH)];
    }

    int lane = tid & 63;
    int g = lane >> 2;
    int q = lane & 3;
    int wv = tid >> 6;
    int dd = wv * 16 + g;              // dest slot within block, 0..63
    int v = blockIdx.x * 64 + dd;
    bool live = (v < n);
    if (!live) v = n - 1;
    int s = start[v], d = deg[v];
    float dv = dis[v];

    float acc[8];
#pragma unroll
    for (int c = 0; c < 8; ++c) acc[c] = 0.f;

    int i = 0;
    for (; i + 8 <= d; i += 8) {
        int u0 = srow[s + i + 0], u1 = srow[s + i + 1], u2 = srow[s + i + 2], u3 = srow[s + i + 3];
        int u4 = srow[s + i + 4], u5 = srow[s + i + 5], u6 = srow[s + i + 6], u7 = srow[s + i + 7];
        uint4 g0 = *reinterpret_cast<const uint4*>(hsh + (size_t)u0 * HID + q * 8);
        uint4 g1 = *reinterpret_cast<const uint4*>(hsh + (size_t)u1 * HID + q * 8);
        uint4 g2 = *reinterpret_cast<const uint4*>(hsh + (size_t)u2 * HID + q * 8);
        uint4 g3 = *reinterpret_cast<const uint4*>(hsh + (size_t)u3 * HID + q * 8);
        uint4 g4 = *reinterpret_cast<const uint4*>(hsh + (size_t)u4 * HID + q * 8);
        uint4 g5 = *reinterpret_cast<const uint4*>(hsh + (size_t)u5 * HID + q * 8);
        uint4 g6 = *reinterpret_cast<const uint4*>(hsh + (size_t)u6 * HID + q * 8);
        uint4 g7 = *reinterpret_cast<const uint4*>(hsh + (size_t)u7 * HID + q * 8);
        ACC8(g0) ACC8(g1) ACC8(g2) ACC8(g3) ACC8(g4) ACC8(g5) ACC8(g6) ACC8(g7)
    }
    for (; i < d; ++i) {
        int u = srow[s + i];
        uint4 gv = *reinterpret_cast<const uint4*>(hsh + (size_t)u * HID + q * 8);
        ACC8(gv)
    }

    uint4 sv4 = *reinterpret_cast<const uint4*>(hsh + (size_t)v * HID + q * 8);
    float self[8] = {bflo(sv4.x), bfhi(sv4.x), bflo(sv4.y), bfhi(sv4.y),
                     bflo(sv4.z), bfhi(sv4.z), bflo(sv4.w), bfhi(sv4.w)};
#pragma unroll
    for (int c = 0; c < 8; ++c)
        svec[dd][q * 8 + c] = dv * (acc[c] + self[c]);
    __syncthreads();

    // epilogue: thread = (dest dd2, out-octet oo); out channels oo*8..oo*8+7 of 32 (=16 mu + 16 lv)
    int dd2 = tid >> 2;
    int oo = tid & 3;
    int v2 = blockIdx.x * 64 + dd2;
    if (v2 >= n) return;
    float o[8];
#pragma unroll
    for (int c = 0; c < 8; ++c) o[c] = 0.f;
#pragma unroll 8
    for (int k = 0; k < 32; ++k) {
        float skv = svec[dd2][k];
        const float* wr = &wc[k][oo * 8];
        o[0] = fmaf(skv, wr[0], o[0]);
        o[1] = fmaf(skv, wr[1], o[1]);
        o[2] = fmaf(skv, wr[2], o[2]);
        o[3] = fmaf(skv, wr[3], o[3]);
        o[4] = fmaf(skv, wr[4], o[4]);
        o[5] = fmaf(skv, wr[5], o[5]);
        o[6] = fmaf(skv, wr[6], o[6]);
        o[7] = fmaf(skv, wr[7], o[7]);
    }
    float* dst;
    const float* bsrc;
    if (oo < 2) { dst = out + (size_t)v2 * OUT_CH + oo * 8;                       bsrc = bmu + oo * 8; }
    else        { dst = out + (size_t)N_NODES * OUT_CH + (size_t)v2 * OUT_CH + (oo - 2) * 8; bsrc = blv + (oo - 2) * 8; }
    float4 b0 = *reinterpret_cast<const float4*>(bsrc);
    float4 b1v = *reinterpret_cast<const float4*>(bsrc + 4);
    *reinterpret_cast<float4*>(dst)     = make_float4(o[0] + b0.x, o[1] + b0.y, o[2] + b0.z, o[3] + b0.w);
    *reinterpret_cast<float4*>(dst + 4) = make_float4(o[4] + b1v.x, o[5] + b1v.y, o[6] + b1v.z, o[7] + b1v.w);
}

// ---------------- launch ----------------

extern "C" void kernel_launch(void* const* d_in, const int* in_sizes, int n_in,
                              void* d_out, int out_size, void* d_ws, size_t ws_size,
                              hipStream_t stream) {
    const float* x   = (const float*)d_in[0];
    const int*   ei  = (const int*)d_in[1];
    const float* W1  = (const float*)d_in[2];
    const float* b1  = (const float*)d_in[3];
    const float* Wmu = (const float*)d_in[4];
    const float* bmu = (const float*)d_in[5];
    const float* Wlv = (const float*)d_in[6];
    const float* blv = (const float*)d_in[7];
    float* out = (float*)d_out;

    const int* row = ei;            // edge_index[0]
    const int* col = ei + E_EDGES;  // edge_index[1]

    char* w = (char*)d_ws;
    int*   bcnt   = (int*)w;  w += 1024;
    int*   bstart = (int*)w;  w += 1024;
    int*   ghist  = (int*)w;  w += (size_t)PB * B_BUCKETS * 4;   // 256 KB
    int*   deg    = (int*)w;  w += (size_t)N_NODES * 4;
    float* dis    = (float*)w; w += (size_t)N_NODES * 4;
    int*   start  = (int*)w;  w += (size_t)N_NODES * 4;
    int*   srow   = (int*)w;  w += (size_t)E_EDGES * 4;
    u16*   h0sh   = (u16*)w;  w += (size_t)N_NODES * HID * 2;
    u16*   hsh    = (u16*)w;  w += (size_t)N_NODES * HID * 2;
    unsigned* psrc = (unsigned*)w; w += (size_t)E_EDGES * 4;

    const int TB = 256;
    k_pre<<<PB + GEMM_BLOCKS, TB, 0, stream>>>(col, ghist, W1, x, h0sh, E_EDGES, N_NODES);
    k_scan<<<B_BUCKETS, 256, 0, stream>>>(ghist, bcnt);
    k_bscan<<<1, 256, 0, stream>>>(bcnt, bstart);
    k_place<<<PB, TB, 0, stream>>>(row, col, bstart, ghist, bcnt, psrc);
    k_bsort<<<B_BUCKETS, 512, 0, stream>>>(psrc, bstart, srow, deg, start, dis, h0sh);
    k_agg1<<<(N_NODES + 63) / 64, TB, 0, stream>>>(h0sh, srow, start, deg, dis, b1, hsh, N_NODES);
    k_agg2<<<(N_NODES + 63) / 64, TB, 0, stream>>>(hsh, srow, start, deg, dis,
                                                   Wmu, Wlv, bmu, blv, out, N_NODES);
}

// Round 19
// 170.506 us; speedup vs baseline: 1.2505x; 1.0762x over previous
//
#include <hip/hip_runtime.h>

#define N_NODES 100000
#define E_EDGES 3200000
#define IN_CH 256
#define HID 32
#define OUT_CH 16

#define B_BUCKETS 250     // buckets over nodes
#define NPB 400           // nodes per bucket (250*400 = 100000 exactly)
#define CAP 20000         // LDS staging capacity in k_bsort
#define PB 256            // partition blocks
#define PCH (E_EDGES / PB)                  // 12500 exactly
#define GEMM_BLOCKS ((N_NODES + 63) / 64)   // 1563

typedef unsigned short u16;
typedef __attribute__((ext_vector_type(8))) short bf16x8;
typedef __attribute__((ext_vector_type(4))) float f32x4;

__device__ __forceinline__ unsigned bf16rtn(float f) {
    unsigned u = __float_as_uint(f);
    return (u + 0x7FFFu + ((u >> 16) & 1u)) >> 16;   // round-to-nearest-even, finite inputs
}
__device__ __forceinline__ float bflo(unsigned u) { return __uint_as_float(u << 16); }
__device__ __forceinline__ float bfhi(unsigned u) { return __uint_as_float(u & 0xFFFF0000u); }

// ---------------- k_pre: hist (blocks 0..255, ghist rows) || MFMA gemm1 (blocks 256..) ----------------

__global__ __launch_bounds__(256) void k_pre(const int* __restrict__ col,
                                             int* __restrict__ ghist,
                                             const float* __restrict__ W1,
                                             const float* __restrict__ x,
                                             u16* __restrict__ h0sh, int e, int n) {
    int bid = blockIdx.x;
    int tid = threadIdx.x;
    if (bid < PB) {
        __shared__ int h[B_BUCKETS];
        for (int i = tid; i < B_BUCKETS; i += 256) h[i] = 0;
        __syncthreads();
        int lo = bid * PCH, hi = lo + PCH;
        for (int i = lo + tid; i < hi; i += 256)
            atomicAdd(&h[col[i] / NPB], 1);
        __syncthreads();
        for (int i = tid; i < B_BUCKETS; i += 256)
            ghist[bid * B_BUCKETS + i] = h[i];           // coalesced row
    } else {
        int gbid = bid - PB;
        int lane = tid & 63;
        int wv = tid >> 6;
        int vbase = gbid * 64 + wv * 16;
        if (vbase >= n) return;             // N multiple of 16
        int arow = lane & 15;
        int kg = lane >> 4;
        const float* xr = x + (size_t)(vbase + arow) * IN_CH + kg * 8;

        // B-fragments straight from W1: elem j of (kt,ct) = W1[kt*32+(lane>>4)*8+j][ct*16+(lane&15)]
        uint4 bfrag[8][2];
        int colc0 = lane & 15;
        int krow0 = (lane >> 4) * 8;
#pragma unroll
        for (int kt = 0; kt < 8; ++kt) {
#pragma unroll
            for (int ct = 0; ct < 2; ++ct) {
                const float* wp = W1 + (size_t)(kt * 32 + krow0) * HID + ct * 16 + colc0;
                unsigned p[4];
#pragma unroll
                for (int pp = 0; pp < 4; ++pp) {
                    unsigned lo = bf16rtn(wp[(2 * pp) * HID]);
                    unsigned hi = bf16rtn(wp[(2 * pp + 1) * HID]);
                    p[pp] = lo | (hi << 16);
                }
                bfrag[kt][ct] = make_uint4(p[0], p[1], p[2], p[3]);
            }
        }

        f32x4 acc0 = {0.f, 0.f, 0.f, 0.f};
        f32x4 acc1 = {0.f, 0.f, 0.f, 0.f};
#pragma unroll
        for (int kt = 0; kt < 8; ++kt) {
            float4 a0 = *reinterpret_cast<const float4*>(xr + kt * 32);
            float4 a1 = *reinterpret_cast<const float4*>(xr + kt * 32 + 4);
            union { unsigned u[4]; bf16x8 v; } af;
            af.u[0] = bf16rtn(a0.x) | (bf16rtn(a0.y) << 16);
            af.u[1] = bf16rtn(a0.z) | (bf16rtn(a0.w) << 16);
            af.u[2] = bf16rtn(a1.x) | (bf16rtn(a1.y) << 16);
            af.u[3] = bf16rtn(a1.z) | (bf16rtn(a1.w) << 16);
            union { uint4 q; bf16x8 v; } b0, b1;
            b0.q = bfrag[kt][0];
            b1.q = bfrag[kt][1];
            acc0 = __builtin_amdgcn_mfma_f32_16x16x32_bf16(af.v, b0.v, acc0, 0, 0, 0);
            acc1 = __builtin_amdgcn_mfma_f32_16x16x32_bf16(af.v, b1.v, acc1, 0, 0, 0);
        }

        int r0 = (lane >> 4) * 4;
        int colo = lane & 15;
#pragma unroll
        for (int r = 0; r < 4; ++r) {
            int v = vbase + r0 + r;
            h0sh[(size_t)v * HID + colo]      = (u16)bf16rtn(acc0[r]);   // unscaled; dis applied in k_bsort
            h0sh[(size_t)v * HID + 16 + colo] = (u16)bf16rtn(acc1[r]);
        }
    }
}

// ---------------- k_scan: per-bucket exclusive prefix over the 256 block counts ----------------

__global__ __launch_bounds__(256) void k_scan(int* __restrict__ ghist, int* __restrict__ bcnt) {
    __shared__ int a[256], b[256];
    int bu = blockIdx.x, t = threadIdx.x;
    int v = ghist[t * B_BUCKETS + bu];
    a[t] = v;
    __syncthreads();
    int* sp = a; int* dp = b;
    for (int off = 1; off < 256; off <<= 1) {
        dp[t] = sp[t] + ((t >= off) ? sp[t - off] : 0);
        __syncthreads();
        int* tm = sp; sp = dp; dp = tm;
    }
    ghist[t * B_BUCKETS + bu] = sp[t] - v;   // exclusive over blocks
    if (t == 255) bcnt[bu] = sp[t];
}

// ---------------- k_bscan: scan bucket totals -> bstart ----------------

__global__ void k_bscan(const int* __restrict__ bcnt, int* __restrict__ bstart) {
    __shared__ int a[256], b[256];
    int t = threadIdx.x;
    int myc = (t < B_BUCKETS) ? bcnt[t] : 0;
    a[t] = myc;
    __syncthreads();
    int* sp = a; int* dp = b;
    for (int off = 1; off < 256; off <<= 1) {
        dp[t] = sp[t] + ((t >= off) ? sp[t - off] : 0);
        __syncthreads();
        int* tm = sp; sp = dp; dp = tm;
    }
    int incl = sp[t];
    if (t < B_BUCKETS) bstart[t] = incl - myc;
    if (t == B_BUCKETS - 1) bstart[B_BUCKETS] = incl;
}

// ---------------- k_place: LDS-reorder partition, coalesced psrc writes, no global atomics ----------------

__global__ __launch_bounds__(256) void k_place(const int* __restrict__ row,
                                               const int* __restrict__ col,
                                               const int* __restrict__ bstart,
                                               const int* __restrict__ ghist,
                                               const int* __restrict__ bcnt,
                                               unsigned* __restrict__ psrc) {
    __shared__ unsigned stage[PCH];          // 50 KB
    __shared__ unsigned char bb[PCH];        // 12.5 KB
    __shared__ int base[B_BUCKETS];
    __shared__ int lstart[B_BUCKETS];
    __shared__ int cur[B_BUCKETS];
    __shared__ int sa[256], sb[256];
    int bid = blockIdx.x;
    int tid = threadIdx.x;

    int h = 0;
    if (tid < B_BUCKETS) {
        int e0 = ghist[bid * B_BUCKETS + tid];
        int e1 = (bid < PB - 1) ? ghist[(bid + 1) * B_BUCKETS + tid] : bcnt[tid];
        base[tid] = bstart[tid] + e0;
        h = e1 - e0;                         // this block's count for bucket tid
    }
    sa[tid] = h;
    __syncthreads();
    int* sp = sa; int* dp = sb;
    for (int off = 1; off < 256; off <<= 1) {
        dp[tid] = sp[tid] + ((tid >= off) ? sp[tid - off] : 0);
        __syncthreads();
        int* tm = sp; sp = dp; dp = tm;
    }
    int ex = sp[tid] - h;
    if (tid < B_BUCKETS) { lstart[tid] = ex; cur[tid] = ex; }
    __syncthreads();

    int lo = bid * PCH;
    for (int i = lo + tid; i < lo + PCH; i += 256) {
        int c = col[i];
        int b = c / NPB;
        int pos = atomicAdd(&cur[b], 1);
        stage[pos] = ((unsigned)(c - b * NPB) << 17) | (unsigned)row[i];
        bb[pos] = (unsigned char)b;
    }
    __syncthreads();

    for (int idx = tid; idx < PCH; idx += 256) {
        int b = bb[idx];
        psrc[base[b] + (idx - lstart[b])] = stage[idx];   // bucket runs in order -> coalesced
    }
}

// ---------------- k_bsort: bucket sort -> srow/deg/start/dis, then scale h0sh ----------------

__global__ __launch_bounds__(512) void k_bsort(const unsigned* __restrict__ psrc,
                                               const int* __restrict__ bstart,
                                               int* __restrict__ srow, int* __restrict__ deg,
                                               int* __restrict__ start, float* __restrict__ dis,
                                               u16* __restrict__ h0sh) {
    __shared__ unsigned buf[CAP];
    __shared__ int cnt[512];
    __shared__ int sa[512];
    __shared__ int sb[512];
    int b = blockIdx.x, t = threadIdx.x;
    int s0 = bstart[b], s1 = bstart[b + 1], len = s1 - s0;

    cnt[t] = 0;
    __syncthreads();
    for (int i = t; i < len; i += 512)
        atomicAdd(&cnt[psrc[s0 + i] >> 17], 1);
    __syncthreads();

    sa[t] = cnt[t];
    __syncthreads();
    int* sp = sa; int* dp = sb;
    for (int off = 1; off < 512; off <<= 1) {
        dp[t] = sp[t] + ((t >= off) ? sp[t - off] : 0);
        __syncthreads();
        int* tm = sp; sp = dp; dp = tm;
    }
    int ex = sp[t] - cnt[t];
    __syncthreads();
    sa[t] = ex;
    sb[t] = ex;
    float dvv = 0.f;
    if (t < NPB) {
        int node = b * NPB + t;
        int d = cnt[t];
        deg[node] = d;
        start[node] = s0 + ex;
        dvv = rsqrtf((float)(d + 1));
        dis[node] = dvv;
    }
    __syncthreads();

    bool fits = (len <= CAP);
    for (int i = t; i < len; i += 512) {
        unsigned p = psrc[s0 + i];
        int cl = (int)(p >> 17);
        int pos = atomicAdd(&sb[cl], 1);
        if (fits) buf[pos] = p & 0x1FFFFu;
        else      srow[s0 + pos] = (int)(p & 0x1FFFFu);
    }
    __syncthreads();
    if (fits)
        for (int i = t; i < len; i += 512)
            srow[s0 + i] = (int)buf[i];

    // scale phase: h0sh[v] *= dis[v] (in place; block owns its 400 nodes exclusively)
    if (t < NPB) {
        int node = b * NPB + t;
        uint4* p4 = reinterpret_cast<uint4*>(h0sh + (size_t)node * HID);
#pragma unroll
        for (int qq = 0; qq < 4; ++qq) {
            uint4 pv = p4[qq];
            unsigned r[4];
            unsigned comp[4] = {pv.x, pv.y, pv.z, pv.w};
#pragma unroll
            for (int k = 0; k < 4; ++k) {
                float lo = bflo(comp[k]) * dvv;
                float hi = bfhi(comp[k]) * dvv;
                r[k] = bf16rtn(lo) | (bf16rtn(hi) << 16);
            }
            p4[qq] = make_uint4(r[0], r[1], r[2], r[3]);
        }
    }
}

// 8 FMAs of one gathered uint4 (8 bf16) into acc[8]
#define ACC8(gv)                                   \
    acc[0] += bflo(gv.x); acc[1] += bfhi(gv.x);    \
    acc[2] += bflo(gv.y); acc[3] += bfhi(gv.y);    \
    acc[4] += bflo(gv.z); acc[5] += bfhi(gv.z);    \
    acc[6] += bflo(gv.w); acc[7] += bfhi(gv.w);

// batch-16 gather: 16 named idx loads, 16 named uint4 gathers, then 128 adds
#define GATHER16(TAB)                                                                            \
    for (; i + 16 <= d; i += 16) {                                                               \
        int u0 = srow[s+i+0], u1 = srow[s+i+1], u2 = srow[s+i+2], u3 = srow[s+i+3];              \
        int u4 = srow[s+i+4], u5 = srow[s+i+5], u6 = srow[s+i+6], u7 = srow[s+i+7];              \
        int u8 = srow[s+i+8], u9 = srow[s+i+9], ua = srow[s+i+10], ub = srow[s+i+11];            \
        int uc = srow[s+i+12], ud = srow[s+i+13], ue = srow[s+i+14], uf = srow[s+i+15];          \
        uint4 g0 = *reinterpret_cast<const uint4*>(TAB + (size_t)u0 * HID + q * 8);              \
        uint4 g1 = *reinterpret_cast<const uint4*>(TAB + (size_t)u1 * HID + q * 8);              \
        uint4 g2 = *reinterpret_cast<const uint4*>(TAB + (size_t)u2 * HID + q * 8);              \
        uint4 g3 = *reinterpret_cast<const uint4*>(TAB + (size_t)u3 * HID + q * 8);              \
        uint4 g4 = *reinterpret_cast<const uint4*>(TAB + (size_t)u4 * HID + q * 8);              \
        uint4 g5 = *reinterpret_cast<const uint4*>(TAB + (size_t)u5 * HID + q * 8);              \
        uint4 g6 = *reinterpret_cast<const uint4*>(TAB + (size_t)u6 * HID + q * 8);              \
        uint4 g7 = *reinterpret_cast<const uint4*>(TAB + (size_t)u7 * HID + q * 8);              \
        uint4 g8 = *reinterpret_cast<const uint4*>(TAB + (size_t)u8 * HID + q * 8);              \
        uint4 g9 = *reinterpret_cast<const uint4*>(TAB + (size_t)u9 * HID + q * 8);              \
        uint4 ga = *reinterpret_cast<const uint4*>(TAB + (size_t)ua * HID + q * 8);              \
        uint4 gb = *reinterpret_cast<const uint4*>(TAB + (size_t)ub * HID + q * 8);              \
        uint4 gc = *reinterpret_cast<const uint4*>(TAB + (size_t)uc * HID + q * 8);              \
        uint4 gd = *reinterpret_cast<const uint4*>(TAB + (size_t)ud * HID + q * 8);              \
        uint4 ge = *reinterpret_cast<const uint4*>(TAB + (size_t)ue * HID + q * 8);              \
        uint4 gf = *reinterpret_cast<const uint4*>(TAB + (size_t)uf * HID + q * 8);              \
        ACC8(g0) ACC8(g1) ACC8(g2) ACC8(g3) ACC8(g4) ACC8(g5) ACC8(g6) ACC8(g7)                  \
        ACC8(g8) ACC8(g9) ACC8(ga) ACC8(gb) ACC8(gc) ACC8(gd) ACC8(ge) ACC8(gf)                  \
    }                                                                                            \
    for (; i + 8 <= d; i += 8) {                                                                 \
        int u0 = srow[s+i+0], u1 = srow[s+i+1], u2 = srow[s+i+2], u3 = srow[s+i+3];              \
        int u4 = srow[s+i+4], u5 = srow[s+i+5], u6 = srow[s+i+6], u7 = srow[s+i+7];              \
        uint4 g0 = *reinterpret_cast<const uint4*>(TAB + (size_t)u0 * HID + q * 8);              \
        uint4 g1 = *reinterpret_cast<const uint4*>(TAB + (size_t)u1 * HID + q * 8);              \
        uint4 g2 = *reinterpret_cast<const uint4*>(TAB + (size_t)u2 * HID + q * 8);              \
        uint4 g3 = *reinterpret_cast<const uint4*>(TAB + (size_t)u3 * HID + q * 8);              \
        uint4 g4 = *reinterpret_cast<const uint4*>(TAB + (size_t)u4 * HID + q * 8);              \
        uint4 g5 = *reinterpret_cast<const uint4*>(TAB + (size_t)u5 * HID + q * 8);              \
        uint4 g6 = *reinterpret_cast<const uint4*>(TAB + (size_t)u6 * HID + q * 8);              \
        uint4 g7 = *reinterpret_cast<const uint4*>(TAB + (size_t)u7 * HID + q * 8);              \
        ACC8(g0) ACC8(g1) ACC8(g2) ACC8(g3) ACC8(g4) ACC8(g5) ACC8(g6) ACC8(g7)                  \
    }                                                                                            \
    for (; i < d; ++i) {                                                                         \
        int u = srow[s + i];                                                                     \
        uint4 gv = *reinterpret_cast<const uint4*>(TAB + (size_t)u * HID + q * 8);               \
        ACC8(gv)                                                                                 \
    }

// ---------------- aggregation 1: hsh = bf16( dis * relu(dv*(sum h0s_u + h0s_v) + b1) ) ----------------
// 16 dests/wave, 4 lanes/dest, lane covers 8 channels (16B gather), batch-16 named scalars.

__global__ __launch_bounds__(256, 4) void k_agg1(const u16* __restrict__ h0sh,
                                                 const int* __restrict__ srow,
                                                 const int* __restrict__ start,
                                                 const int* __restrict__ deg,
                                                 const float* __restrict__ dis,
                                                 const float* __restrict__ b1,
                                                 u16* __restrict__ hsh, int n) {
    int tid = threadIdx.x;
    int lane = tid & 63;
    int g = lane >> 2;          // dest within wave, 0..15
    int q = lane & 3;           // channel-octet, 0..3
    int wv = tid >> 6;
    int v = blockIdx.x * 64 + wv * 16 + g;
    if (v >= n) v = n - 1;
    int s = start[v], d = deg[v];
    float dv = dis[v];

    float acc[8];
#pragma unroll
    for (int c = 0; c < 8; ++c) acc[c] = 0.f;

    int i = 0;
    GATHER16(h0sh)

    uint4 sv = *reinterpret_cast<const uint4*>(h0sh + (size_t)v * HID + q * 8);
    float self[8] = {bflo(sv.x), bfhi(sv.x), bflo(sv.y), bfhi(sv.y),
                     bflo(sv.z), bfhi(sv.z), bflo(sv.w), bfhi(sv.w)};
    float4 ba = *reinterpret_cast<const float4*>(b1 + q * 8);
    float4 bb = *reinterpret_cast<const float4*>(b1 + q * 8 + 4);
    float bias[8] = {ba.x, ba.y, ba.z, ba.w, bb.x, bb.y, bb.z, bb.w};

    unsigned pk[4];
#pragma unroll
    for (int p = 0; p < 4; ++p) {
        float o0 = dv * fmaxf(0.f, fmaf(dv, acc[2 * p] + self[2 * p], bias[2 * p]));
        float o1 = dv * fmaxf(0.f, fmaf(dv, acc[2 * p + 1] + self[2 * p + 1], bias[2 * p + 1]));
        pk[p] = bf16rtn(o0) | (bf16rtn(o1) << 16);
    }
    *reinterpret_cast<uint4*>(hsh + (size_t)v * HID + q * 8) = make_uint4(pk[0], pk[1], pk[2], pk[3]);
}

// ---------------- aggregation 2 + FUSED output transform ----------------

__global__ __launch_bounds__(256, 4) void k_agg2(const u16* __restrict__ hsh,
                                                 const int* __restrict__ srow,
                                                 const int* __restrict__ start,
                                                 const int* __restrict__ deg,
                                                 const float* __restrict__ dis,
                                                 const float* __restrict__ Wmu,
                                                 const float* __restrict__ Wlv,
                                                 const float* __restrict__ bmu,
                                                 const float* __restrict__ blv,
                                                 float* __restrict__ out, int n) {
    __shared__ float wc[32][33];       // [Wmu | Wlv]
    __shared__ float svec[64][33];     // per-block aggregated s vectors (64 dests)
    int tid = threadIdx.x;
    for (int i2 = tid; i2 < 32 * 32; i2 += 256) {
        int k = i2 >> 5, c = i2 & 31;
        wc[k][c] = (c < OUT_CH) ? Wmu[k * OUT_CH + c] : Wlv[k * OUT_CH + (c - OUT_CH)];
    }

    int lane = tid & 63;
    int g = lane >> 2;
    int q = lane & 3;
    int wv = tid >> 6;
    int dd = wv * 16 + g;              // dest slot within block, 0..63
    int v = blockIdx.x * 64 + dd;
    if (v >= n) v = n - 1;
    int s = start[v], d = deg[v];
    float dv = dis[v];

    float acc[8];
#pragma unroll
    for (int c = 0; c < 8; ++c) acc[c] = 0.f;

    int i = 0;
    GATHER16(hsh)

    uint4 sv4 = *reinterpret_cast<const uint4*>(hsh + (size_t)v * HID + q * 8);
    float self[8] = {bflo(sv4.x), bfhi(sv4.x), bflo(sv4.y), bfhi(sv4.y),
                     bflo(sv4.z), bfhi(sv4.z), bflo(sv4.w), bfhi(sv4.w)};
#pragma unroll
    for (int c = 0; c < 8; ++c)
        svec[dd][q * 8 + c] = dv * (acc[c] + self[c]);
    __syncthreads();

    // epilogue: thread = (dest dd2, out-octet oo)
    int dd2 = tid >> 2;
    int oo = tid & 3;
    int v2 = blockIdx.x * 64 + dd2;
    if (v2 >= n) return;
    float o[8];
#pragma unroll
    for (int c = 0; c < 8; ++c) o[c] = 0.f;
#pragma unroll 8
    for (int k = 0; k < 32; ++k) {
        float skv = svec[dd2][k];
        const float* wr = &wc[k][oo * 8];
        o[0] = fmaf(skv, wr[0], o[0]);
        o[1] = fmaf(skv, wr[1], o[1]);
        o[2] = fmaf(skv, wr[2], o[2]);
        o[3] = fmaf(skv, wr[3], o[3]);
        o[4] = fmaf(skv, wr[4], o[4]);
        o[5] = fmaf(skv, wr[5], o[5]);
        o[6] = fmaf(skv, wr[6], o[6]);
        o[7] = fmaf(skv, wr[7], o[7]);
    }
    float* dst;
    const float* bsrc;
    if (oo < 2) { dst = out + (size_t)v2 * OUT_CH + oo * 8;                       bsrc = bmu + oo * 8; }
    else        { dst = out + (size_t)N_NODES * OUT_CH + (size_t)v2 * OUT_CH + (oo - 2) * 8; bsrc = blv + (oo - 2) * 8; }
    float4 b0 = *reinterpret_cast<const float4*>(bsrc);
    float4 b1v = *reinterpret_cast<const float4*>(bsrc + 4);
    *reinterpret_cast<float4*>(dst)     = make_float4(o[0] + b0.x, o[1] + b0.y, o[2] + b0.z, o[3] + b0.w);
    *reinterpret_cast<float4*>(dst + 4) = make_float4(o[4] + b1v.x, o[5] + b1v.y, o[6] + b1v.z, o[7] + b1v.w);
}

// ---------------- launch ----------------

extern "C" void kernel_launch(void* const* d_in, const int* in_sizes, int n_in,
                              void* d_out, int out_size, void* d_ws, size_t ws_size,
                              hipStream_t stream) {
    const float* x   = (const float*)d_in[0];
    const int*   ei  = (const int*)d_in[1];
    const float* W1  = (const float*)d_in[2];
    const float* b1  = (const float*)d_in[3];
    const float* Wmu = (const float*)d_in[4];
    const float* bmu = (const float*)d_in[5];
    const float* Wlv = (const float*)d_in[6];
    const float* blv = (const float*)d_in[7];
    float* out = (float*)d_out;

    const int* row = ei;            // edge_index[0]
    const int* col = ei + E_EDGES;  // edge_index[1]

    char* w = (char*)d_ws;
    int*   bcnt   = (int*)w;  w += 1024;
    int*   bstart = (int*)w;  w += 1024;
    int*   ghist  = (int*)w;  w += (size_t)PB * B_BUCKETS * 4;   // 256 KB
    int*   deg    = (int*)w;  w += (size_t)N_NODES * 4;
    float* dis    = (float*)w; w += (size_t)N_NODES * 4;
    int*   start  = (int*)w;  w += (size_t)N_NODES * 4;
    int*   srow   = (int*)w;  w += (size_t)E_EDGES * 4;
    u16*   h0sh   = (u16*)w;  w += (size_t)N_NODES * HID * 2;
    u16*   hsh    = (u16*)w;  w += (size_t)N_NODES * HID * 2;
    unsigned* psrc = (unsigned*)w; w += (size_t)E_EDGES * 4;

    const int TB = 256;
    k_pre<<<PB + GEMM_BLOCKS, TB, 0, stream>>>(col, ghist, W1, x, h0sh, E_EDGES, N_NODES);
    k_scan<<<B_BUCKETS, 256, 0, stream>>>(ghist, bcnt);
    k_bscan<<<1, 256, 0, stream>>>(bcnt, bstart);
    k_place<<<PB, TB, 0, stream>>>(row, col, bstart, ghist, bcnt, psrc);
    k_bsort<<<B_BUCKETS, 512, 0, stream>>>(psrc, bstart, srow, deg, start, dis, h0sh);
    k_agg1<<<(N_NODES + 63) / 64, TB, 0, stream>>>(h0sh, srow, start, deg, dis, b1, hsh, N_NODES);
    k_agg2<<<(N_NODES + 63) / 64, TB, 0, stream>>>(hsh, srow, start, deg, dis,
                                                   Wmu, Wlv, bmu, blv, out, N_NODES);
}

// Round 20
// 169.667 us; speedup vs baseline: 1.2567x; 1.0049x over previous
//
#include <hip/hip_runtime.h>

#define N_NODES 100000
#define E_EDGES 3200000
#define IN_CH 256
#define HID 32
#define OUT_CH 16

#define B_BUCKETS 250     // buckets over nodes
#define NPB 400           // nodes per bucket (250*400 = 100000 exactly)
#define PB 256            // partition blocks
#define PCH (E_EDGES / PB)                  // 12500 exactly
#define GEMM_BLOCKS ((N_NODES + 63) / 64)   // 1563
#define PADSTRIDE 6416                      // per-bucket extra room: 400*15 pads + 16 align

typedef unsigned short u16;
typedef __attribute__((ext_vector_type(8))) short bf16x8;
typedef __attribute__((ext_vector_type(4))) float f32x4;

__device__ __forceinline__ unsigned bf16rtn(float f) {
    unsigned u = __float_as_uint(f);
    return (u + 0x7FFFu + ((u >> 16) & 1u)) >> 16;   // round-to-nearest-even, finite inputs
}
__device__ __forceinline__ float bflo(unsigned u) { return __uint_as_float(u << 16); }
__device__ __forceinline__ float bfhi(unsigned u) { return __uint_as_float(u & 0xFFFF0000u); }

// ---------------- k_pre: hist (blocks 0..255, ghist rows) || MFMA gemm1 (blocks 256..) ----------------

__global__ __launch_bounds__(256) void k_pre(const int* __restrict__ col,
                                             int* __restrict__ ghist,
                                             const float* __restrict__ W1,
                                             const float* __restrict__ x,
                                             u16* __restrict__ h0sh, int e, int n) {
    int bid = blockIdx.x;
    int tid = threadIdx.x;
    if (bid < PB) {
        __shared__ int h[B_BUCKETS];
        for (int i = tid; i < B_BUCKETS; i += 256) h[i] = 0;
        __syncthreads();
        int lo = bid * PCH, hi = lo + PCH;
        for (int i = lo + tid; i < hi; i += 256)
            atomicAdd(&h[col[i] / NPB], 1);
        __syncthreads();
        for (int i = tid; i < B_BUCKETS; i += 256)
            ghist[bid * B_BUCKETS + i] = h[i];           // coalesced row
    } else {
        int gbid = bid - PB;
        int lane = tid & 63;
        int wv = tid >> 6;
        int vbase = gbid * 64 + wv * 16;
        if (vbase >= n) return;             // N multiple of 16
        int arow = lane & 15;
        int kg = lane >> 4;
        const float* xr = x + (size_t)(vbase + arow) * IN_CH + kg * 8;

        // B-fragments straight from W1: elem j of (kt,ct) = W1[kt*32+(lane>>4)*8+j][ct*16+(lane&15)]
        uint4 bfrag[8][2];
        int colc0 = lane & 15;
        int krow0 = (lane >> 4) * 8;
#pragma unroll
        for (int kt = 0; kt < 8; ++kt) {
#pragma unroll
            for (int ct = 0; ct < 2; ++ct) {
                const float* wp = W1 + (size_t)(kt * 32 + krow0) * HID + ct * 16 + colc0;
                unsigned p[4];
#pragma unroll
                for (int pp = 0; pp < 4; ++pp) {
                    unsigned lo = bf16rtn(wp[(2 * pp) * HID]);
                    unsigned hi = bf16rtn(wp[(2 * pp + 1) * HID]);
                    p[pp] = lo | (hi << 16);
                }
                bfrag[kt][ct] = make_uint4(p[0], p[1], p[2], p[3]);
            }
        }

        f32x4 acc0 = {0.f, 0.f, 0.f, 0.f};
        f32x4 acc1 = {0.f, 0.f, 0.f, 0.f};
#pragma unroll
        for (int kt = 0; kt < 8; ++kt) {
            float4 a0 = *reinterpret_cast<const float4*>(xr + kt * 32);
            float4 a1 = *reinterpret_cast<const float4*>(xr + kt * 32 + 4);
            union { unsigned u[4]; bf16x8 v; } af;
            af.u[0] = bf16rtn(a0.x) | (bf16rtn(a0.y) << 16);
            af.u[1] = bf16rtn(a0.z) | (bf16rtn(a0.w) << 16);
            af.u[2] = bf16rtn(a1.x) | (bf16rtn(a1.y) << 16);
            af.u[3] = bf16rtn(a1.z) | (bf16rtn(a1.w) << 16);
            union { uint4 q; bf16x8 v; } b0, b1;
            b0.q = bfrag[kt][0];
            b1.q = bfrag[kt][1];
            acc0 = __builtin_amdgcn_mfma_f32_16x16x32_bf16(af.v, b0.v, acc0, 0, 0, 0);
            acc1 = __builtin_amdgcn_mfma_f32_16x16x32_bf16(af.v, b1.v, acc1, 0, 0, 0);
        }

        int r0 = (lane >> 4) * 4;
        int colo = lane & 15;
#pragma unroll
        for (int r = 0; r < 4; ++r) {
            int v = vbase + r0 + r;
            h0sh[(size_t)v * HID + colo]      = (u16)bf16rtn(acc0[r]);   // unscaled; dis applied in k_bsort
            h0sh[(size_t)v * HID + 16 + colo] = (u16)bf16rtn(acc1[r]);
        }
    }
}

// ---------------- k_scan: per-bucket exclusive prefix over the 256 block counts ----------------

__global__ __launch_bounds__(256) void k_scan(int* __restrict__ ghist, int* __restrict__ bcnt) {
    __shared__ int a[256], b[256];
    int bu = blockIdx.x, t = threadIdx.x;
    int v = ghist[t * B_BUCKETS + bu];
    a[t] = v;
    __syncthreads();
    int* sp = a; int* dp = b;
    for (int off = 1; off < 256; off <<= 1) {
        dp[t] = sp[t] + ((t >= off) ? sp[t - off] : 0);
        __syncthreads();
        int* tm = sp; sp = dp; dp = tm;
    }
    ghist[t * B_BUCKETS + bu] = sp[t] - v;   // exclusive over blocks
    if (t == 255) bcnt[bu] = sp[t];
}

// ---------------- k_bscan: scan bucket totals -> bstart; zero pad-rows of tables ----------------

__global__ void k_bscan(const int* __restrict__ bcnt, int* __restrict__ bstart,
                        u16* __restrict__ h0sh, u16* __restrict__ hsh) {
    __shared__ int a[256], b[256];
    int t = threadIdx.x;
    if (t < HID) {                     // zero row N_NODES of both gather tables
        h0sh[(size_t)N_NODES * HID + t] = 0;
        hsh[(size_t)N_NODES * HID + t] = 0;
    }
    int myc = (t < B_BUCKETS) ? bcnt[t] : 0;
    a[t] = myc;
    __syncthreads();
    int* sp = a; int* dp = b;
    for (int off = 1; off < 256; off <<= 1) {
        dp[t] = sp[t] + ((t >= off) ? sp[t - off] : 0);
        __syncthreads();
        int* tm = sp; sp = dp; dp = tm;
    }
    int incl = sp[t];
    if (t < B_BUCKETS) bstart[t] = incl - myc;
    if (t == B_BUCKETS - 1) bstart[B_BUCKETS] = incl;
}

// ---------------- k_place: LDS-reorder partition, coalesced psrc writes, no global atomics ----------------

__global__ __launch_bounds__(256) void k_place(const int* __restrict__ row,
                                               const int* __restrict__ col,
                                               const int* __restrict__ bstart,
                                               const int* __restrict__ ghist,
                                               const int* __restrict__ bcnt,
                                               unsigned* __restrict__ psrc) {
    __shared__ unsigned stage[PCH];          // 50 KB
    __shared__ unsigned char bb[PCH];        // 12.5 KB
    __shared__ int base[B_BUCKETS];
    __shared__ int lstart[B_BUCKETS];
    __shared__ int cur[B_BUCKETS];
    __shared__ int sa[256], sb[256];
    int bid = blockIdx.x;
    int tid = threadIdx.x;

    int h = 0;
    if (tid < B_BUCKETS) {
        int e0 = ghist[bid * B_BUCKETS + tid];
        int e1 = (bid < PB - 1) ? ghist[(bid + 1) * B_BUCKETS + tid] : bcnt[tid];
        base[tid] = bstart[tid] + e0;
        h = e1 - e0;                         // this block's count for bucket tid
    }
    sa[tid] = h;
    __syncthreads();
    int* sp = sa; int* dp = sb;
    for (int off = 1; off < 256; off <<= 1) {
        dp[tid] = sp[tid] + ((tid >= off) ? sp[tid - off] : 0);
        __syncthreads();
        int* tm = sp; sp = dp; dp = tm;
    }
    int ex = sp[tid] - h;
    if (tid < B_BUCKETS) { lstart[tid] = ex; cur[tid] = ex; }
    __syncthreads();

    int lo = bid * PCH;
    for (int i = lo + tid; i < lo + PCH; i += 256) {
        int c = col[i];
        int b = c / NPB;
        int pos = atomicAdd(&cur[b], 1);
        stage[pos] = ((unsigned)(c - b * NPB) << 17) | (unsigned)row[i];
        bb[pos] = (unsigned char)b;
    }
    __syncthreads();

    for (int idx = tid; idx < PCH; idx += 256) {
        int b = bb[idx];
        psrc[base[b] + (idx - lstart[b])] = stage[idx];   // bucket runs in order -> coalesced
    }
}

// ---------------- k_bsort: bucket sort -> PADDED srow (16-multiples), deg/start/dis, scale h0sh ----------------
// Node segments 16-aligned and padded to multiples of 16 with index N_NODES (zero row).

__global__ __launch_bounds__(512) void k_bsort(const unsigned* __restrict__ psrc,
                                               const int* __restrict__ bstart,
                                               int* __restrict__ srow, int* __restrict__ deg,
                                               int* __restrict__ start, float* __restrict__ dis,
                                               u16* __restrict__ h0sh) {
    __shared__ int cnt[512];
    __shared__ int sa[512];
    __shared__ int sb[512];
    __shared__ int cur[512];
    int b = blockIdx.x, t = threadIdx.x;
    int s0 = bstart[b], s1 = bstart[b + 1], len = s1 - s0;
    int pbase = ((s0 + 15) & ~15) + b * PADSTRIDE;   // 16-aligned padded bucket base

    cnt[t] = 0;
    __syncthreads();
    for (int i = t; i < len; i += 512)
        atomicAdd(&cnt[psrc[s0 + i] >> 17], 1);
    __syncthreads();

    int d = cnt[t];
    int dpad = (d + 15) & ~15;
    sa[t] = dpad;
    __syncthreads();
    int* sp = sa; int* dp = sb;
    for (int off = 1; off < 512; off <<= 1) {
        dp[t] = sp[t] + ((t >= off) ? sp[t - off] : 0);
        __syncthreads();
        int* tm = sp; sp = dp; dp = tm;
    }
    int pex = sp[t] - dpad;                  // padded exclusive prefix
    __syncthreads();
    int gstart = pbase + pex;
    cur[t] = gstart;                         // per-node global cursor
    float dvv = 0.f;
    if (t < NPB) {
        int node = b * NPB + t;
        deg[node] = d;
        start[node] = gstart;
        dvv = rsqrtf((float)(d + 1));
        dis[node] = dvv;
        for (int j = d; j < dpad; ++j)       // fill pads with zero-row index
            srow[gstart + j] = N_NODES;
    }
    __syncthreads();

    for (int i = t; i < len; i += 512) {
        unsigned p = psrc[s0 + i];
        int cl = (int)(p >> 17);
        int pos = atomicAdd(&cur[cl], 1);
        srow[pos] = (int)(p & 0x1FFFFu);     // scattered, bucket-local (~80KB) -> L2 merges
    }

    // scale phase: h0sh[v] *= dis[v] (in place; block owns its 400 nodes exclusively)
    if (t < NPB) {
        int node = b * NPB + t;
        uint4* p4 = reinterpret_cast<uint4*>(h0sh + (size_t)node * HID);
#pragma unroll
        for (int qq = 0; qq < 4; ++qq) {
            uint4 pv = p4[qq];
            unsigned r[4];
            unsigned comp[4] = {pv.x, pv.y, pv.z, pv.w};
#pragma unroll
            for (int k = 0; k < 4; ++k) {
                float lo = bflo(comp[k]) * dvv;
                float hi = bfhi(comp[k]) * dvv;
                r[k] = bf16rtn(lo) | (bf16rtn(hi) << 16);
            }
            p4[qq] = make_uint4(r[0], r[1], r[2], r[3]);
        }
    }
}

// 8 FMAs of one gathered uint4 (8 bf16) into acc[8]
#define ACC8(gv)                                   \
    acc[0] += bflo(gv.x); acc[1] += bfhi(gv.x);    \
    acc[2] += bflo(gv.y); acc[3] += bfhi(gv.y);    \
    acc[4] += bflo(gv.z); acc[5] += bfhi(gv.z);    \
    acc[6] += bflo(gv.w); acc[7] += bfhi(gv.w);

// batch-16 gather with VECTOR index loads (segments 16-aligned, dpad multiple of 16, no tails)
#define GATHER16V(TAB)                                                                           \
    for (int i = 0; i < dpad; i += 16) {                                                         \
        int4 ui0 = *reinterpret_cast<const int4*>(srow + s + i);                                 \
        int4 ui1 = *reinterpret_cast<const int4*>(srow + s + i + 4);                             \
        int4 ui2 = *reinterpret_cast<const int4*>(srow + s + i + 8);                             \
        int4 ui3 = *reinterpret_cast<const int4*>(srow + s + i + 12);                            \
        uint4 g0 = *reinterpret_cast<const uint4*>(TAB + (size_t)ui0.x * HID + q * 8);           \
        uint4 g1 = *reinterpret_cast<const uint4*>(TAB + (size_t)ui0.y * HID + q * 8);           \
        uint4 g2 = *reinterpret_cast<const uint4*>(TAB + (size_t)ui0.z * HID + q * 8);           \
        uint4 g3 = *reinterpret_cast<const uint4*>(TAB + (size_t)ui0.w * HID + q * 8);           \
        uint4 g4 = *reinterpret_cast<const uint4*>(TAB + (size_t)ui1.x * HID + q * 8);           \
        uint4 g5 = *reinterpret_cast<const uint4*>(TAB + (size_t)ui1.y * HID + q * 8);           \
        uint4 g6 = *reinterpret_cast<const uint4*>(TAB + (size_t)ui1.z * HID + q * 8);           \
        uint4 g7 = *reinterpret_cast<const uint4*>(TAB + (size_t)ui1.w * HID + q * 8);           \
        uint4 g8 = *reinterpret_cast<const uint4*>(TAB + (size_t)ui2.x * HID + q * 8);           \
        uint4 g9 = *reinterpret_cast<const uint4*>(TAB + (size_t)ui2.y * HID + q * 8);           \
        uint4 ga = *reinterpret_cast<const uint4*>(TAB + (size_t)ui2.z * HID + q * 8);           \
        uint4 gb = *reinterpret_cast<const uint4*>(TAB + (size_t)ui2.w * HID + q * 8);           \
        uint4 gc = *reinterpret_cast<const uint4*>(TAB + (size_t)ui3.x * HID + q * 8);           \
        uint4 gd = *reinterpret_cast<const uint4*>(TAB + (size_t)ui3.y * HID + q * 8);           \
        uint4 ge = *reinterpret_cast<const uint4*>(TAB + (size_t)ui3.z * HID + q * 8);           \
        uint4 gf = *reinterpret_cast<const uint4*>(TAB + (size_t)ui3.w * HID + q * 8);           \
        ACC8(g0) ACC8(g1) ACC8(g2) ACC8(g3) ACC8(g4) ACC8(g5) ACC8(g6) ACC8(g7)                  \
        ACC8(g8) ACC8(g9) ACC8(ga) ACC8(gb) ACC8(gc) ACC8(gd) ACC8(ge) ACC8(gf)                  \
    }

// ---------------- aggregation 1: hsh = bf16( dis * relu(dv*(sum h0s_u + h0s_v) + b1) ) ----------------

__global__ __launch_bounds__(256, 4) void k_agg1(const u16* __restrict__ h0sh,
                                                 const int* __restrict__ srow,
                                                 const int* __restrict__ start,
                                                 const int* __restrict__ deg,
                                                 const float* __restrict__ dis,
                                                 const float* __restrict__ b1,
                                                 u16* __restrict__ hsh, int n) {
    int tid = threadIdx.x;
    int lane = tid & 63;
    int g = lane >> 2;          // dest within wave, 0..15
    int q = lane & 3;           // channel-octet, 0..3
    int wv = tid >> 6;
    int v = blockIdx.x * 64 + wv * 16 + g;
    if (v >= n) v = n - 1;
    int s = start[v];
    int dpad = (deg[v] + 15) & ~15;
    float dv = dis[v];

    float acc[8];
#pragma unroll
    for (int c = 0; c < 8; ++c) acc[c] = 0.f;

    GATHER16V(h0sh)

    uint4 sv = *reinterpret_cast<const uint4*>(h0sh + (size_t)v * HID + q * 8);
    float self[8] = {bflo(sv.x), bfhi(sv.x), bflo(sv.y), bfhi(sv.y),
                     bflo(sv.z), bfhi(sv.z), bflo(sv.w), bfhi(sv.w)};
    float4 ba = *reinterpret_cast<const float4*>(b1 + q * 8);
    float4 bb = *reinterpret_cast<const float4*>(b1 + q * 8 + 4);
    float bias[8] = {ba.x, ba.y, ba.z, ba.w, bb.x, bb.y, bb.z, bb.w};

    unsigned pk[4];
#pragma unroll
    for (int p = 0; p < 4; ++p) {
        float o0 = dv * fmaxf(0.f, fmaf(dv, acc[2 * p] + self[2 * p], bias[2 * p]));
        float o1 = dv * fmaxf(0.f, fmaf(dv, acc[2 * p + 1] + self[2 * p + 1], bias[2 * p + 1]));
        pk[p] = bf16rtn(o0) | (bf16rtn(o1) << 16);
    }
    *reinterpret_cast<uint4*>(hsh + (size_t)v * HID + q * 8) = make_uint4(pk[0], pk[1], pk[2], pk[3]);
}

// ---------------- aggregation 2 + FUSED output transform ----------------

__global__ __launch_bounds__(256, 4) void k_agg2(const u16* __restrict__ hsh,
                                                 const int* __restrict__ srow,
                                                 const int* __restrict__ start,
                                                 const int* __restrict__ deg,
                                                 const float* __restrict__ dis,
                                                 const float* __restrict__ Wmu,
                                                 const float* __restrict__ Wlv,
                                                 const float* __restrict__ bmu,
                                                 const float* __restrict__ blv,
                                                 float* __restrict__ out, int n) {
    __shared__ float wc[32][33];       // [Wmu | Wlv]
    __shared__ float svec[64][33];     // per-block aggregated s vectors (64 dests)
    int tid = threadIdx.x;
    for (int i2 = tid; i2 < 32 * 32; i2 += 256) {
        int k = i2 >> 5, c = i2 & 31;
        wc[k][c] = (c < OUT_CH) ? Wmu[k * OUT_CH + c] : Wlv[k * OUT_CH + (c - OUT_CH)];
    }

    int lane = tid & 63;
    int g = lane >> 2;
    int q = lane & 3;
    int wv = tid >> 6;
    int dd = wv * 16 + g;              // dest slot within block, 0..63
    int v = blockIdx.x * 64 + dd;
    if (v >= n) v = n - 1;
    int s = start[v];
    int dpad = (deg[v] + 15) & ~15;
    float dv = dis[v];

    float acc[8];
#pragma unroll
    for (int c = 0; c < 8; ++c) acc[c] = 0.f;

    GATHER16V(hsh)

    uint4 sv4 = *reinterpret_cast<const uint4*>(hsh + (size_t)v * HID + q * 8);
    float self[8] = {bflo(sv4.x), bfhi(sv4.x), bflo(sv4.y), bfhi(sv4.y),
                     bflo(sv4.z), bfhi(sv4.z), bflo(sv4.w), bfhi(sv4.w)};
#pragma unroll
    for (int c = 0; c < 8; ++c)
        svec[dd][q * 8 + c] = dv * (acc[c] + self[c]);
    __syncthreads();

    // epilogue: thread = (dest dd2, out-octet oo)
    int dd2 = tid >> 2;
    int oo = tid & 3;
    int v2 = blockIdx.x * 64 + dd2;
    if (v2 >= n) return;
    float o[8];
#pragma unroll
    for (int c = 0; c < 8; ++c) o[c] = 0.f;
#pragma unroll 8
    for (int k = 0; k < 32; ++k) {
        float skv = svec[dd2][k];
        const float* wr = &wc[k][oo * 8];
        o[0] = fmaf(skv, wr[0], o[0]);
        o[1] = fmaf(skv, wr[1], o[1]);
        o[2] = fmaf(skv, wr[2], o[2]);
        o[3] = fmaf(skv, wr[3], o[3]);
        o[4] = fmaf(skv, wr[4], o[4]);
        o[5] = fmaf(skv, wr[5], o[5]);
        o[6] = fmaf(skv, wr[6], o[6]);
        o[7] = fmaf(skv, wr[7], o[7]);
    }
    float* dst;
    const float* bsrc;
    if (oo < 2) { dst = out + (size_t)v2 * OUT_CH + oo * 8;                       bsrc = bmu + oo * 8; }
    else        { dst = out + (size_t)N_NODES * OUT_CH + (size_t)v2 * OUT_CH + (oo - 2) * 8; bsrc = blv + (oo - 2) * 8; }
    float4 b0 = *reinterpret_cast<const float4*>(bsrc);
    float4 b1v = *reinterpret_cast<const float4*>(bsrc + 4);
    *reinterpret_cast<float4*>(dst)     = make_float4(o[0] + b0.x, o[1] + b0.y, o[2] + b0.z, o[3] + b0.w);
    *reinterpret_cast<float4*>(dst + 4) = make_float4(o[4] + b1v.x, o[5] + b1v.y, o[6] + b1v.z, o[7] + b1v.w);
}

// ---------------- launch ----------------

extern "C" void kernel_launch(void* const* d_in, const int* in_sizes, int n_in,
                              void* d_out, int out_size, void* d_ws, size_t ws_size,
                              hipStream_t stream) {
    const float* x   = (const float*)d_in[0];
    const int*   ei  = (const int*)d_in[1];
    const float* W1  = (const float*)d_in[2];
    const float* b1  = (const float*)d_in[3];
    const float* Wmu = (const float*)d_in[4];
    const float* bmu = (const float*)d_in[5];
    const float* Wlv = (const float*)d_in[6];
    const float* blv = (const float*)d_in[7];
    float* out = (float*)d_out;

    const int* row = ei;            // edge_index[0]
    const int* col = ei + E_EDGES;  // edge_index[1]

    char* w = (char*)d_ws;
    int*   bcnt   = (int*)w;  w += 1024;
    int*   bstart = (int*)w;  w += 1024;
    int*   ghist  = (int*)w;  w += (size_t)PB * B_BUCKETS * 4;     // 256 KB
    int*   deg    = (int*)w;  w += (size_t)N_NODES * 4;
    float* dis    = (float*)w; w += (size_t)N_NODES * 4;
    int*   start  = (int*)w;  w += (size_t)N_NODES * 4;
    int*   srow   = (int*)w;  w += (size_t)(E_EDGES + 16 + B_BUCKETS * PADSTRIDE) * 4;  // padded CSR
    u16*   h0sh   = (u16*)w;  w += (size_t)(N_NODES + 1) * HID * 2;  // +1 zero row
    u16*   hsh    = (u16*)w;  w += (size_t)(N_NODES + 1) * HID * 2;
    unsigned* psrc = (unsigned*)w; w += (size_t)E_EDGES * 4;

    const int TB = 256;
    k_pre<<<PB + GEMM_BLOCKS, TB, 0, stream>>>(col, ghist, W1, x, h0sh, E_EDGES, N_NODES);
    k_scan<<<B_BUCKETS, 256, 0, stream>>>(ghist, bcnt);
    k_bscan<<<1, 256, 0, stream>>>(bcnt, bstart, h0sh, hsh);
    k_place<<<PB, TB, 0, stream>>>(row, col, bstart, ghist, bcnt, psrc);
    k_bsort<<<B_BUCKETS, 512, 0, stream>>>(psrc, bstart, srow, deg, start, dis, h0sh);
    k_agg1<<<(N_NODES + 63) / 64, TB, 0, stream>>>(h0sh, srow, start, deg, dis, b1, hsh, N_NODES);
    k_agg2<<<(N_NODES + 63) / 64, TB, 0, stream>>>(hsh, srow, start, deg, dis,
                                                   Wmu, Wlv, bmu, blv, out, N_NODES);
}

// Round 21
// 154.023 us; speedup vs baseline: 1.3843x; 1.1016x over previous
//
#include <hip/hip_runtime.h>

#define N_NODES 100000
#define E_EDGES 3200000
#define IN_CH 256
#define HID 32
#define OUT_CH 16

#define B_BUCKETS 250     // buckets over nodes
#define NPB 400           // nodes per bucket (250*400 = 100000 exactly)
#define PB 512            // partition blocks
#define PCH (E_EDGES / PB)                  // 6250 exactly
#define GEMM_BLOCKS ((N_NODES + 63) / 64)   // 1563
#define PADSTRIDE 6416                      // per-bucket pad room: 400*15 pads + 16 align

typedef unsigned short u16;
typedef __attribute__((ext_vector_type(8))) short bf16x8;
typedef __attribute__((ext_vector_type(4))) float f32x4;

__device__ __forceinline__ unsigned bf16rtn(float f) {
    unsigned u = __float_as_uint(f);
    return (u + 0x7FFFu + ((u >> 16) & 1u)) >> 16;   // round-to-nearest-even, finite inputs
}
__device__ __forceinline__ float bflo(unsigned u) { return __uint_as_float(u << 16); }
__device__ __forceinline__ float bfhi(unsigned u) { return __uint_as_float(u & 0xFFFF0000u); }

// ---------------- k_pre: hist (blocks 0..511, ghist rows) | W1 fragment pack (block 512) ----------------

__global__ __launch_bounds__(256) void k_pre(const int* __restrict__ col,
                                             int* __restrict__ ghist,
                                             const float* __restrict__ W1,
                                             uint4* __restrict__ W1f, int e) {
    int bid = blockIdx.x;
    int tid = threadIdx.x;
    if (bid < PB) {
        __shared__ int h[B_BUCKETS];
        for (int i = tid; i < B_BUCKETS; i += 256) h[i] = 0;
        __syncthreads();
        int lo = bid * PCH, hi = lo + PCH;
        for (int i = lo + tid; i < hi; i += 256)
            atomicAdd(&h[col[i] / NPB], 1);
        __syncthreads();
        for (int i = tid; i < B_BUCKETS; i += 256)
            ghist[bid * B_BUCKETS + i] = h[i];           // coalesced row
    } else {
        // W1f[(kt*2+ct)*64+lane]: elem j = W1[kt*32+(lane>>4)*8+j][ct*16+(lane&15)]
        for (int s = tid; s < 1024; s += 256) {
            int lane = s & 63;
            int ctkt = s >> 6;
            int ct = ctkt & 1, kt = ctkt >> 1;
            int colc = ct * 16 + (lane & 15);
            int k0 = kt * 32 + (lane >> 4) * 8;
            unsigned p[4];
#pragma unroll
            for (int pp = 0; pp < 4; ++pp) {
                unsigned lo = bf16rtn(W1[(k0 + 2 * pp) * HID + colc]);
                unsigned hi = bf16rtn(W1[(k0 + 2 * pp + 1) * HID + colc]);
                p[pp] = lo | (hi << 16);
            }
            W1f[s] = make_uint4(p[0], p[1], p[2], p[3]);
        }
    }
}

// ---------------- k_scan: per-bucket exclusive prefix over the 512 block counts ----------------

__global__ __launch_bounds__(512) void k_scan(int* __restrict__ ghist, int* __restrict__ bcnt) {
    __shared__ int a[512], b[512];
    int bu = blockIdx.x, t = threadIdx.x;
    int v = ghist[t * B_BUCKETS + bu];
    a[t] = v;
    __syncthreads();
    int* sp = a; int* dp = b;
    for (int off = 1; off < 512; off <<= 1) {
        dp[t] = sp[t] + ((t >= off) ? sp[t - off] : 0);
        __syncthreads();
        int* tm = sp; sp = dp; dp = tm;
    }
    ghist[t * B_BUCKETS + bu] = sp[t] - v;   // exclusive over blocks
    if (t == 511) bcnt[bu] = sp[t];
}

// ---------------- k_bscan: scan bucket totals -> bstart; zero pad-rows of tables ----------------

__global__ void k_bscan(const int* __restrict__ bcnt, int* __restrict__ bstart,
                        u16* __restrict__ h0sh, u16* __restrict__ hsh) {
    __shared__ int a[256], b[256];
    int t = threadIdx.x;
    if (t < HID) {                     // zero row N_NODES of both gather tables
        h0sh[(size_t)N_NODES * HID + t] = 0;
        hsh[(size_t)N_NODES * HID + t] = 0;
    }
    int myc = (t < B_BUCKETS) ? bcnt[t] : 0;
    a[t] = myc;
    __syncthreads();
    int* sp = a; int* dp = b;
    for (int off = 1; off < 256; off <<= 1) {
        dp[t] = sp[t] + ((t >= off) ? sp[t - off] : 0);
        __syncthreads();
        int* tm = sp; sp = dp; dp = tm;
    }
    int incl = sp[t];
    if (t < B_BUCKETS) bstart[t] = incl - myc;
    if (t == B_BUCKETS - 1) bstart[B_BUCKETS] = incl;
}

// ---------------- k_place: LDS-reorder partition (blocks 0..511) || MFMA gemm1 (512..) ----------------
// W1f produced by k_pre (previous dispatch) -> ordering guaranteed.

__global__ __launch_bounds__(256) void k_place(const int* __restrict__ row,
                                               const int* __restrict__ col,
                                               const int* __restrict__ bstart,
                                               const int* __restrict__ ghist,
                                               const int* __restrict__ bcnt,
                                               unsigned* __restrict__ psrc,
                                               const float* __restrict__ x,
                                               const uint4* __restrict__ W1f,
                                               u16* __restrict__ h0sh, int n) {
    __shared__ unsigned stage[PCH];          // 25 KB
    __shared__ unsigned char bb[PCH];        // 6.25 KB
    __shared__ int base[B_BUCKETS];
    __shared__ int lstart[B_BUCKETS];
    __shared__ int cur[B_BUCKETS];
    __shared__ int sa[256], sb[256];
    int bid = blockIdx.x;
    int tid = threadIdx.x;

    if (bid < PB) {
        int h = 0;
        if (tid < B_BUCKETS) {
            int e0 = ghist[bid * B_BUCKETS + tid];
            int e1 = (bid < PB - 1) ? ghist[(bid + 1) * B_BUCKETS + tid] : bcnt[tid];
            base[tid] = bstart[tid] + e0;
            h = e1 - e0;                         // this block's count for bucket tid
        }
        sa[tid] = h;
        __syncthreads();
        int* sp = sa; int* dp = sb;
        for (int off = 1; off < 256; off <<= 1) {
            dp[tid] = sp[tid] + ((tid >= off) ? sp[tid - off] : 0);
            __syncthreads();
            int* tm = sp; sp = dp; dp = tm;
        }
        int ex = sp[tid] - h;
        if (tid < B_BUCKETS) { lstart[tid] = ex; cur[tid] = ex; }
        __syncthreads();

        int lo = bid * PCH;
        for (int i = lo + tid; i < lo + PCH; i += 256) {
            int c = col[i];
            int b = c / NPB;
            int pos = atomicAdd(&cur[b], 1);
            stage[pos] = ((unsigned)(c - b * NPB) << 17) | (unsigned)row[i];
            bb[pos] = (unsigned char)b;
        }
        __syncthreads();

        for (int idx = tid; idx < PCH; idx += 256) {
            int b = bb[idx];
            psrc[base[b] + (idx - lstart[b])] = stage[idx];   // bucket runs in order -> coalesced
        }
    } else {
        int gbid = bid - PB;
        int lane = tid & 63;
        int wv = tid >> 6;
        int vbase = gbid * 64 + wv * 16;
        if (vbase >= n) return;             // N multiple of 16
        int arow = lane & 15;
        int kg = lane >> 4;
        const float* xr = x + (size_t)(vbase + arow) * IN_CH + kg * 8;

        uint4 bfrag[8][2];
#pragma unroll
        for (int kt = 0; kt < 8; ++kt) {
#pragma unroll
            for (int ct = 0; ct < 2; ++ct)
                bfrag[kt][ct] = W1f[(kt * 2 + ct) * 64 + lane];
        }

        f32x4 acc0 = {0.f, 0.f, 0.f, 0.f};
        f32x4 acc1 = {0.f, 0.f, 0.f, 0.f};
#pragma unroll
        for (int kt = 0; kt < 8; ++kt) {
            float4 a0 = *reinterpret_cast<const float4*>(xr + kt * 32);
            float4 a1 = *reinterpret_cast<const float4*>(xr + kt * 32 + 4);
            union { unsigned u[4]; bf16x8 v; } af;
            af.u[0] = bf16rtn(a0.x) | (bf16rtn(a0.y) << 16);
            af.u[1] = bf16rtn(a0.z) | (bf16rtn(a0.w) << 16);
            af.u[2] = bf16rtn(a1.x) | (bf16rtn(a1.y) << 16);
            af.u[3] = bf16rtn(a1.z) | (bf16rtn(a1.w) << 16);
            union { uint4 q; bf16x8 v; } b0, b1;
            b0.q = bfrag[kt][0];
            b1.q = bfrag[kt][1];
            acc0 = __builtin_amdgcn_mfma_f32_16x16x32_bf16(af.v, b0.v, acc0, 0, 0, 0);
            acc1 = __builtin_amdgcn_mfma_f32_16x16x32_bf16(af.v, b1.v, acc1, 0, 0, 0);
        }

        int r0 = (lane >> 4) * 4;
        int colo = lane & 15;
#pragma unroll
        for (int r = 0; r < 4; ++r) {
            int v = vbase + r0 + r;
            h0sh[(size_t)v * HID + colo]      = (u16)bf16rtn(acc0[r]);   // unscaled; dis applied in k_bsort
            h0sh[(size_t)v * HID + 16 + colo] = (u16)bf16rtn(acc1[r]);
        }
    }
}

// ---------------- k_bsort: bucket sort -> PADDED srow (16-multiples), deg/start/dis, scale h0sh ----------------

__global__ __launch_bounds__(512) void k_bsort(const unsigned* __restrict__ psrc,
                                               const int* __restrict__ bstart,
                                               int* __restrict__ srow, int* __restrict__ deg,
                                               int* __restrict__ start, float* __restrict__ dis,
                                               u16* __restrict__ h0sh) {
    __shared__ int cnt[512];
    __shared__ int sa[512];
    __shared__ int sb[512];
    __shared__ int cur[512];
    int b = blockIdx.x, t = threadIdx.x;
    int s0 = bstart[b], s1 = bstart[b + 1], len = s1 - s0;
    int pbase = ((s0 + 15) & ~15) + b * PADSTRIDE;   // 16-aligned padded bucket base

    cnt[t] = 0;
    __syncthreads();
    for (int i = t; i < len; i += 512)
        atomicAdd(&cnt[psrc[s0 + i] >> 17], 1);
    __syncthreads();

    int d = cnt[t];
    int dpad = (d + 15) & ~15;
    sa[t] = dpad;
    __syncthreads();
    int* sp = sa; int* dp = sb;
    for (int off = 1; off < 512; off <<= 1) {
        dp[t] = sp[t] + ((t >= off) ? sp[t - off] : 0);
        __syncthreads();
        int* tm = sp; sp = dp; dp = tm;
    }
    int pex = sp[t] - dpad;                  // padded exclusive prefix
    __syncthreads();
    int gstart = pbase + pex;
    cur[t] = gstart;                         // per-node global cursor
    float dvv = 0.f;
    if (t < NPB) {
        int node = b * NPB + t;
        deg[node] = d;
        start[node] = gstart;
        dvv = rsqrtf((float)(d + 1));
        dis[node] = dvv;
        for (int j = d; j < dpad; ++j)       // fill pads with zero-row index
            srow[gstart + j] = N_NODES;
    }
    __syncthreads();

    for (int i = t; i < len; i += 512) {
        unsigned p = psrc[s0 + i];
        int cl = (int)(p >> 17);
        int pos = atomicAdd(&cur[cl], 1);
        srow[pos] = (int)(p & 0x1FFFFu);     // scattered, bucket-local -> L2 merges
    }

    // scale phase: h0sh[v] *= dis[v] (in place; block owns its 400 nodes exclusively)
    if (t < NPB) {
        int node = b * NPB + t;
        uint4* p4 = reinterpret_cast<uint4*>(h0sh + (size_t)node * HID);
#pragma unroll
        for (int qq = 0; qq < 4; ++qq) {
            uint4 pv = p4[qq];
            unsigned r[4];
            unsigned comp[4] = {pv.x, pv.y, pv.z, pv.w};
#pragma unroll
            for (int k = 0; k < 4; ++k) {
                float lo = bflo(comp[k]) * dvv;
                float hi = bfhi(comp[k]) * dvv;
                r[k] = bf16rtn(lo) | (bf16rtn(hi) << 16);
            }
            p4[qq] = make_uint4(r[0], r[1], r[2], r[3]);
        }
    }
}

// 8 FMAs of one gathered uint4 (8 bf16) into acc[8]
#define ACC8(gv)                                   \
    acc[0] += bflo(gv.x); acc[1] += bfhi(gv.x);    \
    acc[2] += bflo(gv.y); acc[3] += bfhi(gv.y);    \
    acc[4] += bflo(gv.z); acc[5] += bfhi(gv.z);    \
    acc[6] += bflo(gv.w); acc[7] += bfhi(gv.w);

// batch-16 gather with VECTOR index loads (segments 16-aligned, dpad multiple of 16, no tails)
#define GATHER16V(TAB)                                                                           \
    for (int i = 0; i < dpad; i += 16) {                                                         \
        int4 ui0 = *reinterpret_cast<const int4*>(srow + s + i);                                 \
        int4 ui1 = *reinterpret_cast<const int4*>(srow + s + i + 4);                             \
        int4 ui2 = *reinterpret_cast<const int4*>(srow + s + i + 8);                             \
        int4 ui3 = *reinterpret_cast<const int4*>(srow + s + i + 12);                            \
        uint4 g0 = *reinterpret_cast<const uint4*>(TAB + (size_t)ui0.x * HID + q * 8);           \
        uint4 g1 = *reinterpret_cast<const uint4*>(TAB + (size_t)ui0.y * HID + q * 8);           \
        uint4 g2 = *reinterpret_cast<const uint4*>(TAB + (size_t)ui0.z * HID + q * 8);           \
        uint4 g3 = *reinterpret_cast<const uint4*>(TAB + (size_t)ui0.w * HID + q * 8);           \
        uint4 g4 = *reinterpret_cast<const uint4*>(TAB + (size_t)ui1.x * HID + q * 8);           \
        uint4 g5 = *reinterpret_cast<const uint4*>(TAB + (size_t)ui1.y * HID + q * 8);           \
        uint4 g6 = *reinterpret_cast<const uint4*>(TAB + (size_t)ui1.z * HID + q * 8);           \
        uint4 g7 = *reinterpret_cast<const uint4*>(TAB + (size_t)ui1.w * HID + q * 8);           \
        uint4 g8 = *reinterpret_cast<const uint4*>(TAB + (size_t)ui2.x * HID + q * 8);           \
        uint4 g9 = *reinterpret_cast<const uint4*>(TAB + (size_t)ui2.y * HID + q * 8);           \
        uint4 ga = *reinterpret_cast<const uint4*>(TAB + (size_t)ui2.z * HID + q * 8);           \
        uint4 gb = *reinterpret_cast<const uint4*>(TAB + (size_t)ui2.w * HID + q * 8);           \
        uint4 gc = *reinterpret_cast<const uint4*>(TAB + (size_t)ui3.x * HID + q * 8);           \
        uint4 gd = *reinterpret_cast<const uint4*>(TAB + (size_t)ui3.y * HID + q * 8);           \
        uint4 ge = *reinterpret_cast<const uint4*>(TAB + (size_t)ui3.z * HID + q * 8);           \
        uint4 gf = *reinterpret_cast<const uint4*>(TAB + (size_t)ui3.w * HID + q * 8);           \
        ACC8(g0) ACC8(g1) ACC8(g2) ACC8(g3) ACC8(g4) ACC8(g5) ACC8(g6) ACC8(g7)                  \
        ACC8(g8) ACC8(g9) ACC8(ga) ACC8(gb) ACC8(gc) ACC8(gd) ACC8(ge) ACC8(gf)                  \
    }

// ---------------- aggregation 1: hsh = bf16( dis * relu(dv*(sum h0s_u + h0s_v) + b1) ) ----------------

__global__ __launch_bounds__(256, 4) void k_agg1(const u16* __restrict__ h0sh,
                                                 const int* __restrict__ srow,
                                                 const int* __restrict__ start,
                                                 const int* __restrict__ deg,
                                                 const float* __restrict__ dis,
                                                 const float* __restrict__ b1,
                                                 u16* __restrict__ hsh, int n) {
    int tid = threadIdx.x;
    int lane = tid & 63;
    int g = lane >> 2;          // dest within wave, 0..15
    int q = lane & 3;           // channel-octet, 0..3
    int wv = tid >> 6;
    int v = blockIdx.x * 64 + wv * 16 + g;
    if (v >= n) v = n - 1;
    int s = start[v];
    int dpad = (deg[v] + 15) & ~15;
    float dv = dis[v];

    float acc[8];
#pragma unroll
    for (int c = 0; c < 8; ++c) acc[c] = 0.f;

    GATHER16V(h0sh)

    uint4 sv = *reinterpret_cast<const uint4*>(h0sh + (size_t)v * HID + q * 8);
    float self[8] = {bflo(sv.x), bfhi(sv.x), bflo(sv.y), bfhi(sv.y),
                     bflo(sv.z), bfhi(sv.z), bflo(sv.w), bfhi(sv.w)};
    float4 ba = *reinterpret_cast<const float4*>(b1 + q * 8);
    float4 bb = *reinterpret_cast<const float4*>(b1 + q * 8 + 4);
    float bias[8] = {ba.x, ba.y, ba.z, ba.w, bb.x, bb.y, bb.z, bb.w};

    unsigned pk[4];
#pragma unroll
    for (int p = 0; p < 4; ++p) {
        float o0 = dv * fmaxf(0.f, fmaf(dv, acc[2 * p] + self[2 * p], bias[2 * p]));
        float o1 = dv * fmaxf(0.f, fmaf(dv, acc[2 * p + 1] + self[2 * p + 1], bias[2 * p + 1]));
        pk[p] = bf16rtn(o0) | (bf16rtn(o1) << 16);
    }
    *reinterpret_cast<uint4*>(hsh + (size_t)v * HID + q * 8) = make_uint4(pk[0], pk[1], pk[2], pk[3]);
}

// ---------------- aggregation 2 + FUSED output transform ----------------

__global__ __launch_bounds__(256, 4) void k_agg2(const u16* __restrict__ hsh,
                                                 const int* __restrict__ srow,
                                                 const int* __restrict__ start,
                                                 const int* __restrict__ deg,
                                                 const float* __restrict__ dis,
                                                 const float* __restrict__ Wmu,
                                                 const float* __restrict__ Wlv,
                                                 const float* __restrict__ bmu,
                                                 const float* __restrict__ blv,
                                                 float* __restrict__ out, int n) {
    __shared__ float wc[32][33];       // [Wmu | Wlv]
    __shared__ float svec[64][33];     // per-block aggregated s vectors (64 dests)
    int tid = threadIdx.x;
    for (int i2 = tid; i2 < 32 * 32; i2 += 256) {
        int k = i2 >> 5, c = i2 & 31;
        wc[k][c] = (c < OUT_CH) ? Wmu[k * OUT_CH + c] : Wlv[k * OUT_CH + (c - OUT_CH)];
    }

    int lane = tid & 63;
    int g = lane >> 2;
    int q = lane & 3;
    int wv = tid >> 6;
    int dd = wv * 16 + g;              // dest slot within block, 0..63
    int v = blockIdx.x * 64 + dd;
    if (v >= n) v = n - 1;
    int s = start[v];
    int dpad = (deg[v] + 15) & ~15;
    float dv = dis[v];

    float acc[8];
#pragma unroll
    for (int c = 0; c < 8; ++c) acc[c] = 0.f;

    GATHER16V(hsh)

    uint4 sv4 = *reinterpret_cast<const uint4*>(hsh + (size_t)v * HID + q * 8);
    float self[8] = {bflo(sv4.x), bfhi(sv4.x), bflo(sv4.y), bfhi(sv4.y),
                     bflo(sv4.z), bfhi(sv4.z), bflo(sv4.w), bfhi(sv4.w)};
#pragma unroll
    for (int c = 0; c < 8; ++c)
        svec[dd][q * 8 + c] = dv * (acc[c] + self[c]);
    __syncthreads();

    // epilogue: thread = (dest dd2, out-octet oo)
    int dd2 = tid >> 2;
    int oo = tid & 3;
    int v2 = blockIdx.x * 64 + dd2;
    if (v2 >= n) return;
    float o[8];
#pragma unroll
    for (int c = 0; c < 8; ++c) o[c] = 0.f;
#pragma unroll 8
    for (int k = 0; k < 32; ++k) {
        float skv = svec[dd2][k];
        const float* wr = &wc[k][oo * 8];
        o[0] = fmaf(skv, wr[0], o[0]);
        o[1] = fmaf(skv, wr[1], o[1]);
        o[2] = fmaf(skv, wr[2], o[2]);
        o[3] = fmaf(skv, wr[3], o[3]);
        o[4] = fmaf(skv, wr[4], o[4]);
        o[5] = fmaf(skv, wr[5], o[5]);
        o[6] = fmaf(skv, wr[6], o[6]);
        o[7] = fmaf(skv, wr[7], o[7]);
    }
    float* dst;
    const float* bsrc;
    if (oo < 2) { dst = out + (size_t)v2 * OUT_CH + oo * 8;                       bsrc = bmu + oo * 8; }
    else        { dst = out + (size_t)N_NODES * OUT_CH + (size_t)v2 * OUT_CH + (oo - 2) * 8; bsrc = blv + (oo - 2) * 8; }
    float4 b0 = *reinterpret_cast<const float4*>(bsrc);
    float4 b1v = *reinterpret_cast<const float4*>(bsrc + 4);
    *reinterpret_cast<float4*>(dst)     = make_float4(o[0] + b0.x, o[1] + b0.y, o[2] + b0.z, o[3] + b0.w);
    *reinterpret_cast<float4*>(dst + 4) = make_float4(o[4] + b1v.x, o[5] + b1v.y, o[6] + b1v.z, o[7] + b1v.w);
}

// ---------------- launch ----------------

extern "C" void kernel_launch(void* const* d_in, const int* in_sizes, int n_in,
                              void* d_out, int out_size, void* d_ws, size_t ws_size,
                              hipStream_t stream) {
    const float* x   = (const float*)d_in[0];
    const int*   ei  = (const int*)d_in[1];
    const float* W1  = (const float*)d_in[2];
    const float* b1  = (const float*)d_in[3];
    const float* Wmu = (const float*)d_in[4];
    const float* bmu = (const float*)d_in[5];
    const float* Wlv = (const float*)d_in[6];
    const float* blv = (const float*)d_in[7];
    float* out = (float*)d_out;

    const int* row = ei;            // edge_index[0]
    const int* col = ei + E_EDGES;  // edge_index[1]

    char* w = (char*)d_ws;
    int*   bcnt   = (int*)w;  w += 1024;
    int*   bstart = (int*)w;  w += 1024;
    uint4* W1f    = (uint4*)w; w += 16384;                         // 1024 * 16B fragments
    int*   ghist  = (int*)w;  w += (size_t)PB * B_BUCKETS * 4;     // 512 KB
    int*   deg    = (int*)w;  w += (size_t)N_NODES * 4;
    float* dis    = (float*)w; w += (size_t)N_NODES * 4;
    int*   start  = (int*)w;  w += (size_t)N_NODES * 4;
    int*   srow   = (int*)w;  w += (size_t)(E_EDGES + 16 + B_BUCKETS * PADSTRIDE) * 4;  // padded CSR
    u16*   h0sh   = (u16*)w;  w += (size_t)(N_NODES + 1) * HID * 2;  // +1 zero row
    u16*   hsh    = (u16*)w;  w += (size_t)(N_NODES + 1) * HID * 2;
    unsigned* psrc = (unsigned*)w; w += (size_t)E_EDGES * 4;

    const int TB = 256;
    k_pre<<<PB + 1, TB, 0, stream>>>(col, ghist, W1, W1f, E_EDGES);
    k_scan<<<B_BUCKETS, 512, 0, stream>>>(ghist, bcnt);
    k_bscan<<<1, 256, 0, stream>>>(bcnt, bstart, h0sh, hsh);
    k_place<<<PB + GEMM_BLOCKS, TB, 0, stream>>>(row, col, bstart, ghist, bcnt, psrc,
                                                 x, W1f, h0sh, N_NODES);
    k_bsort<<<B_BUCKETS, 512, 0, stream>>>(psrc, bstart, srow, deg, start, dis, h0sh);
    k_agg1<<<(N_NODES + 63) / 64, TB, 0, stream>>>(h0sh, srow, start, deg, dis, b1, hsh, N_NODES);
    k_agg2<<<(N_NODES + 63) / 64, TB, 0, stream>>>(hsh, srow, start, deg, dis,
                                                   Wmu, Wlv, bmu, blv, out, N_NODES);
}

// Round 22
// 149.090 us; speedup vs baseline: 1.4301x; 1.0331x over previous
//
#include <hip/hip_runtime.h>

#define N_NODES 100000
#define E_EDGES 3200000
#define IN_CH 256
#define HID 32
#define OUT_CH 16

#define B_BUCKETS 250     // buckets over nodes
#define NPB 400           // nodes per bucket (250*400 = 100000 exactly)
#define PB 1024           // partition blocks
#define PCH (E_EDGES / PB)                  // 3125 exactly
#define GEMM_BLOCKS ((N_NODES + 63) / 64)   // 1563
#define PADSTRIDE 6416                      // per-bucket pad room: 400*15 pads + 16 align

typedef unsigned short u16;
typedef __attribute__((ext_vector_type(8))) short bf16x8;
typedef __attribute__((ext_vector_type(4))) float f32x4;

__device__ __forceinline__ unsigned bf16rtn(float f) {
    unsigned u = __float_as_uint(f);
    return (u + 0x7FFFu + ((u >> 16) & 1u)) >> 16;   // round-to-nearest-even, finite inputs
}
__device__ __forceinline__ float bflo(unsigned u) { return __uint_as_float(u << 16); }
__device__ __forceinline__ float bfhi(unsigned u) { return __uint_as_float(u & 0xFFFF0000u); }

// ---------------- k_pre: hist (blocks 0..PB-1, ghist rows) | W1 fragment pack (block PB) ----------------

__global__ __launch_bounds__(256) void k_pre(const int* __restrict__ col,
                                             int* __restrict__ ghist,
                                             const float* __restrict__ W1,
                                             uint4* __restrict__ W1f, int e) {
    int bid = blockIdx.x;
    int tid = threadIdx.x;
    if (bid < PB) {
        __shared__ int h[B_BUCKETS];
        for (int i = tid; i < B_BUCKETS; i += 256) h[i] = 0;
        __syncthreads();
        int lo = bid * PCH, hi = lo + PCH;
        for (int i = lo + tid; i < hi; i += 256)
            atomicAdd(&h[col[i] / NPB], 1);
        __syncthreads();
        for (int i = tid; i < B_BUCKETS; i += 256)
            ghist[bid * B_BUCKETS + i] = h[i];           // coalesced row
    } else {
        // W1f[(kt*2+ct)*64+lane]: elem j = W1[kt*32+(lane>>4)*8+j][ct*16+(lane&15)]
        for (int s = tid; s < 1024; s += 256) {
            int lane = s & 63;
            int ctkt = s >> 6;
            int ct = ctkt & 1, kt = ctkt >> 1;
            int colc = ct * 16 + (lane & 15);
            int k0 = kt * 32 + (lane >> 4) * 8;
            unsigned p[4];
#pragma unroll
            for (int pp = 0; pp < 4; ++pp) {
                unsigned lo = bf16rtn(W1[(k0 + 2 * pp) * HID + colc]);
                unsigned hi = bf16rtn(W1[(k0 + 2 * pp + 1) * HID + colc]);
                p[pp] = lo | (hi << 16);
            }
            W1f[s] = make_uint4(p[0], p[1], p[2], p[3]);
        }
    }
}

// ---------------- k_scan: per-bucket exclusive prefix over the PB block counts ----------------

__global__ __launch_bounds__(1024) void k_scan(int* __restrict__ ghist, int* __restrict__ bcnt) {
    __shared__ int a[1024], b[1024];
    int bu = blockIdx.x, t = threadIdx.x;
    int v = ghist[t * B_BUCKETS + bu];
    a[t] = v;
    __syncthreads();
    int* sp = a; int* dp = b;
    for (int off = 1; off < 1024; off <<= 1) {
        dp[t] = sp[t] + ((t >= off) ? sp[t - off] : 0);
        __syncthreads();
        int* tm = sp; sp = dp; dp = tm;
    }
    ghist[t * B_BUCKETS + bu] = sp[t] - v;   // exclusive over blocks
    if (t == 1023) bcnt[bu] = sp[t];
}

// ---------------- k_bscan: scan bucket totals -> bstart; zero pad-rows of tables ----------------

__global__ void k_bscan(const int* __restrict__ bcnt, int* __restrict__ bstart,
                        u16* __restrict__ h0sh, u16* __restrict__ hsh) {
    __shared__ int a[256], b[256];
    int t = threadIdx.x;
    if (t < HID) {                     // zero row N_NODES of both gather tables
        h0sh[(size_t)N_NODES * HID + t] = 0;
        hsh[(size_t)N_NODES * HID + t] = 0;
    }
    int myc = (t < B_BUCKETS) ? bcnt[t] : 0;
    a[t] = myc;
    __syncthreads();
    int* sp = a; int* dp = b;
    for (int off = 1; off < 256; off <<= 1) {
        dp[t] = sp[t] + ((t >= off) ? sp[t - off] : 0);
        __syncthreads();
        int* tm = sp; sp = dp; dp = tm;
    }
    int incl = sp[t];
    if (t < B_BUCKETS) bstart[t] = incl - myc;
    if (t == B_BUCKETS - 1) bstart[B_BUCKETS] = incl;
}

// ---------------- k_place: LDS-reorder partition (blocks 0..PB-1) || MFMA gemm1 (PB..) ----------------
// W1f produced by k_pre (previous dispatch) -> ordering guaranteed. ~21KB LDS -> 7 blocks/CU.

__global__ __launch_bounds__(256) void k_place(const int* __restrict__ row,
                                               const int* __restrict__ col,
                                               const int* __restrict__ bstart,
                                               const int* __restrict__ ghist,
                                               const int* __restrict__ bcnt,
                                               unsigned* __restrict__ psrc,
                                               const float* __restrict__ x,
                                               const uint4* __restrict__ W1f,
                                               u16* __restrict__ h0sh, int n) {
    __shared__ unsigned stage[PCH];          // 12.5 KB
    __shared__ unsigned char bb[PCH];        // 3.1 KB
    __shared__ int base[B_BUCKETS];
    __shared__ int lstart[B_BUCKETS];
    __shared__ int cur[B_BUCKETS];
    __shared__ int sa[256], sb[256];
    int bid = blockIdx.x;
    int tid = threadIdx.x;

    if (bid < PB) {
        int h = 0;
        if (tid < B_BUCKETS) {
            int e0 = ghist[bid * B_BUCKETS + tid];
            int e1 = (bid < PB - 1) ? ghist[(bid + 1) * B_BUCKETS + tid] : bcnt[tid];
            base[tid] = bstart[tid] + e0;
            h = e1 - e0;                         // this block's count for bucket tid
        }
        sa[tid] = h;
        __syncthreads();
        int* sp = sa; int* dp = sb;
        for (int off = 1; off < 256; off <<= 1) {
            dp[tid] = sp[tid] + ((tid >= off) ? sp[tid - off] : 0);
            __syncthreads();
            int* tm = sp; sp = dp; dp = tm;
        }
        int ex = sp[tid] - h;
        if (tid < B_BUCKETS) { lstart[tid] = ex; cur[tid] = ex; }
        __syncthreads();

        int lo = bid * PCH;
        for (int i = lo + tid; i < lo + PCH; i += 256) {
            int c = col[i];
            int b = c / NPB;
            int pos = atomicAdd(&cur[b], 1);
            stage[pos] = ((unsigned)(c - b * NPB) << 17) | (unsigned)row[i];
            bb[pos] = (unsigned char)b;
        }
        __syncthreads();

        for (int idx = tid; idx < PCH; idx += 256) {
            int b = bb[idx];
            psrc[base[b] + (idx - lstart[b])] = stage[idx];   // bucket runs in order
        }
    } else {
        int gbid = bid - PB;
        int lane = tid & 63;
        int wv = tid >> 6;
        int vbase = gbid * 64 + wv * 16;
        if (vbase >= n) return;             // N multiple of 16
        int arow = lane & 15;
        int kg = lane >> 4;
        const float* xr = x + (size_t)(vbase + arow) * IN_CH + kg * 8;

        uint4 bfrag[8][2];
#pragma unroll
        for (int kt = 0; kt < 8; ++kt) {
#pragma unroll
            for (int ct = 0; ct < 2; ++ct)
                bfrag[kt][ct] = W1f[(kt * 2 + ct) * 64 + lane];
        }

        f32x4 acc0 = {0.f, 0.f, 0.f, 0.f};
        f32x4 acc1 = {0.f, 0.f, 0.f, 0.f};
#pragma unroll
        for (int kt = 0; kt < 8; ++kt) {
            float4 a0 = *reinterpret_cast<const float4*>(xr + kt * 32);
            float4 a1 = *reinterpret_cast<const float4*>(xr + kt * 32 + 4);
            union { unsigned u[4]; bf16x8 v; } af;
            af.u[0] = bf16rtn(a0.x) | (bf16rtn(a0.y) << 16);
            af.u[1] = bf16rtn(a0.z) | (bf16rtn(a0.w) << 16);
            af.u[2] = bf16rtn(a1.x) | (bf16rtn(a1.y) << 16);
            af.u[3] = bf16rtn(a1.z) | (bf16rtn(a1.w) << 16);
            union { uint4 q; bf16x8 v; } b0, b1;
            b0.q = bfrag[kt][0];
            b1.q = bfrag[kt][1];
            acc0 = __builtin_amdgcn_mfma_f32_16x16x32_bf16(af.v, b0.v, acc0, 0, 0, 0);
            acc1 = __builtin_amdgcn_mfma_f32_16x16x32_bf16(af.v, b1.v, acc1, 0, 0, 0);
        }

        int r0 = (lane >> 4) * 4;
        int colo = lane & 15;
#pragma unroll
        for (int r = 0; r < 4; ++r) {
            int v = vbase + r0 + r;
            h0sh[(size_t)v * HID + colo]      = (u16)bf16rtn(acc0[r]);   // unscaled; dis applied in k_bsort
            h0sh[(size_t)v * HID + 16 + colo] = (u16)bf16rtn(acc1[r]);
        }
    }
}

// ---------------- k_bsort: bucket sort -> PADDED srow (16-multiples), deg/start/dis, scale h0sh ----------------

__global__ __launch_bounds__(512) void k_bsort(const unsigned* __restrict__ psrc,
                                               const int* __restrict__ bstart,
                                               int* __restrict__ srow, int* __restrict__ deg,
                                               int* __restrict__ start, float* __restrict__ dis,
                                               u16* __restrict__ h0sh) {
    __shared__ int cnt[512];
    __shared__ int sa[512];
    __shared__ int sb[512];
    __shared__ int cur[512];
    int b = blockIdx.x, t = threadIdx.x;
    int s0 = bstart[b], s1 = bstart[b + 1], len = s1 - s0;
    int pbase = ((s0 + 15) & ~15) + b * PADSTRIDE;   // 16-aligned padded bucket base

    cnt[t] = 0;
    __syncthreads();
    for (int i = t; i < len; i += 512)
        atomicAdd(&cnt[psrc[s0 + i] >> 17], 1);
    __syncthreads();

    int d = cnt[t];
    int dpad = (d + 15) & ~15;
    sa[t] = dpad;
    __syncthreads();
    int* sp = sa; int* dp = sb;
    for (int off = 1; off < 512; off <<= 1) {
        dp[t] = sp[t] + ((t >= off) ? sp[t - off] : 0);
        __syncthreads();
        int* tm = sp; sp = dp; dp = tm;
    }
    int pex = sp[t] - dpad;                  // padded exclusive prefix
    __syncthreads();
    int gstart = pbase + pex;
    cur[t] = gstart;                         // per-node global cursor
    float dvv = 0.f;
    if (t < NPB) {
        int node = b * NPB + t;
        deg[node] = d;
        start[node] = gstart;
        dvv = rsqrtf((float)(d + 1));
        dis[node] = dvv;
        for (int j = d; j < dpad; ++j)       // fill pads with zero-row index
            srow[gstart + j] = N_NODES;
    }
    __syncthreads();

    for (int i = t; i < len; i += 512) {
        unsigned p = psrc[s0 + i];
        int cl = (int)(p >> 17);
        int pos = atomicAdd(&cur[cl], 1);
        srow[pos] = (int)(p & 0x1FFFFu);     // scattered, bucket-local -> L2 merges
    }

    // scale phase: h0sh[v] *= dis[v] (in place; block owns its 400 nodes exclusively)
    if (t < NPB) {
        int node = b * NPB + t;
        uint4* p4 = reinterpret_cast<uint4*>(h0sh + (size_t)node * HID);
#pragma unroll
        for (int qq = 0; qq < 4; ++qq) {
            uint4 pv = p4[qq];
            unsigned r[4];
            unsigned comp[4] = {pv.x, pv.y, pv.z, pv.w};
#pragma unroll
            for (int k = 0; k < 4; ++k) {
                float lo = bflo(comp[k]) * dvv;
                float hi = bfhi(comp[k]) * dvv;
                r[k] = bf16rtn(lo) | (bf16rtn(hi) << 16);
            }
            p4[qq] = make_uint4(r[0], r[1], r[2], r[3]);
        }
    }
}

// 8 FMAs of one gathered uint4 (8 bf16) into acc[8]
#define ACC8(gv)                                   \
    acc[0] += bflo(gv.x); acc[1] += bfhi(gv.x);    \
    acc[2] += bflo(gv.y); acc[3] += bfhi(gv.y);    \
    acc[4] += bflo(gv.z); acc[5] += bfhi(gv.z);    \
    acc[6] += bflo(gv.w); acc[7] += bfhi(gv.w);

// batch-16 gather with VECTOR index loads (segments 16-aligned, dpad multiple of 16, no tails)
#define GATHER16V(TAB)                                                                           \
    for (int i = 0; i < dpad; i += 16) {                                                         \
        int4 ui0 = *reinterpret_cast<const int4*>(srow + s + i);                                 \
        int4 ui1 = *reinterpret_cast<const int4*>(srow + s + i + 4);                             \
        int4 ui2 = *reinterpret_cast<const int4*>(srow + s + i + 8);                             \
        int4 ui3 = *reinterpret_cast<const int4*>(srow + s + i + 12);                            \
        uint4 g0 = *reinterpret_cast<const uint4*>(TAB + (size_t)ui0.x * HID + q * 8);           \
        uint4 g1 = *reinterpret_cast<const uint4*>(TAB + (size_t)ui0.y * HID + q * 8);           \
        uint4 g2 = *reinterpret_cast<const uint4*>(TAB + (size_t)ui0.z * HID + q * 8);           \
        uint4 g3 = *reinterpret_cast<const uint4*>(TAB + (size_t)ui0.w * HID + q * 8);           \
        uint4 g4 = *reinterpret_cast<const uint4*>(TAB + (size_t)ui1.x * HID + q * 8);           \
        uint4 g5 = *reinterpret_cast<const uint4*>(TAB + (size_t)ui1.y * HID + q * 8);           \
        uint4 g6 = *reinterpret_cast<const uint4*>(TAB + (size_t)ui1.z * HID + q * 8);           \
        uint4 g7 = *reinterpret_cast<const uint4*>(TAB + (size_t)ui1.w * HID + q * 8);           \
        uint4 g8 = *reinterpret_cast<const uint4*>(TAB + (size_t)ui2.x * HID + q * 8);           \
        uint4 g9 = *reinterpret_cast<const uint4*>(TAB + (size_t)ui2.y * HID + q * 8);           \
        uint4 ga = *reinterpret_cast<const uint4*>(TAB + (size_t)ui2.z * HID + q * 8);           \
        uint4 gb = *reinterpret_cast<const uint4*>(TAB + (size_t)ui2.w * HID + q * 8);           \
        uint4 gc = *reinterpret_cast<const uint4*>(TAB + (size_t)ui3.x * HID + q * 8);           \
        uint4 gd = *reinterpret_cast<const uint4*>(TAB + (size_t)ui3.y * HID + q * 8);           \
        uint4 ge = *reinterpret_cast<const uint4*>(TAB + (size_t)ui3.z * HID + q * 8);           \
        uint4 gf = *reinterpret_cast<const uint4*>(TAB + (size_t)ui3.w * HID + q * 8);           \
        ACC8(g0) ACC8(g1) ACC8(g2) ACC8(g3) ACC8(g4) ACC8(g5) ACC8(g6) ACC8(g7)                  \
        ACC8(g8) ACC8(g9) ACC8(ga) ACC8(gb) ACC8(gc) ACC8(gd) ACC8(ge) ACC8(gf)                  \
    }

// ---------------- aggregation 1: hsh = bf16( dis * relu(dv*(sum h0s_u + h0s_v) + b1) ) ----------------

__global__ __launch_bounds__(256, 4) void k_agg1(const u16* __restrict__ h0sh,
                                                 const int* __restrict__ srow,
                                                 const int* __restrict__ start,
                                                 const int* __restrict__ deg,
                                                 const float* __restrict__ dis,
                                                 const float* __restrict__ b1,
                                                 u16* __restrict__ hsh, int n) {
    int tid = threadIdx.x;
    int lane = tid & 63;
    int g = lane >> 2;          // dest within wave, 0..15
    int q = lane & 3;           // channel-octet, 0..3
    int wv = tid >> 6;
    int v = blockIdx.x * 64 + wv * 16 + g;
    if (v >= n) v = n - 1;
    int s = start[v];
    int dpad = (deg[v] + 15) & ~15;
    float dv = dis[v];

    float acc[8];
#pragma unroll
    for (int c = 0; c < 8; ++c) acc[c] = 0.f;

    GATHER16V(h0sh)

    uint4 sv = *reinterpret_cast<const uint4*>(h0sh + (size_t)v * HID + q * 8);
    float self[8] = {bflo(sv.x), bfhi(sv.x), bflo(sv.y), bfhi(sv.y),
                     bflo(sv.z), bfhi(sv.z), bflo(sv.w), bfhi(sv.w)};
    float4 ba = *reinterpret_cast<const float4*>(b1 + q * 8);
    float4 bb = *reinterpret_cast<const float4*>(b1 + q * 8 + 4);
    float bias[8] = {ba.x, ba.y, ba.z, ba.w, bb.x, bb.y, bb.z, bb.w};

    unsigned pk[4];
#pragma unroll
    for (int p = 0; p < 4; ++p) {
        float o0 = dv * fmaxf(0.f, fmaf(dv, acc[2 * p] + self[2 * p], bias[2 * p]));
        float o1 = dv * fmaxf(0.f, fmaf(dv, acc[2 * p + 1] + self[2 * p + 1], bias[2 * p + 1]));
        pk[p] = bf16rtn(o0) | (bf16rtn(o1) << 16);
    }
    *reinterpret_cast<uint4*>(hsh + (size_t)v * HID + q * 8) = make_uint4(pk[0], pk[1], pk[2], pk[3]);
}

// ---------------- aggregation 2 + FUSED output transform ----------------

__global__ __launch_bounds__(256, 4) void k_agg2(const u16* __restrict__ hsh,
                                                 const int* __restrict__ srow,
                                                 const int* __restrict__ start,
                                                 const int* __restrict__ deg,
                                                 const float* __restrict__ dis,
                                                 const float* __restrict__ Wmu,
                                                 const float* __restrict__ Wlv,
                                                 const float* __restrict__ bmu,
                                                 const float* __restrict__ blv,
                                                 float* __restrict__ out, int n) {
    __shared__ float wc[32][33];       // [Wmu | Wlv]
    __shared__ float svec[64][33];     // per-block aggregated s vectors (64 dests)
    int tid = threadIdx.x;
    for (int i2 = tid; i2 < 32 * 32; i2 += 256) {
        int k = i2 >> 5, c = i2 & 31;
        wc[k][c] = (c < OUT_CH) ? Wmu[k * OUT_CH + c] : Wlv[k * OUT_CH + (c - OUT_CH)];
    }

    int lane = tid & 63;
    int g = lane >> 2;
    int q = lane & 3;
    int wv = tid >> 6;
    int dd = wv * 16 + g;              // dest slot within block, 0..63
    int v = blockIdx.x * 64 + dd;
    if (v >= n) v = n - 1;
    int s = start[v];
    int dpad = (deg[v] + 15) & ~15;
    float dv = dis[v];

    float acc[8];
#pragma unroll
    for (int c = 0; c < 8; ++c) acc[c] = 0.f;

    GATHER16V(hsh)

    uint4 sv4 = *reinterpret_cast<const uint4*>(hsh + (size_t)v * HID + q * 8);
    float self[8] = {bflo(sv4.x), bfhi(sv4.x), bflo(sv4.y), bfhi(sv4.y),
                     bflo(sv4.z), bfhi(sv4.z), bflo(sv4.w), bfhi(sv4.w)};
#pragma unroll
    for (int c = 0; c < 8; ++c)
        svec[dd][q * 8 + c] = dv * (acc[c] + self[c]);
    __syncthreads();

    // epilogue: thread = (dest dd2, out-octet oo)
    int dd2 = tid >> 2;
    int oo = tid & 3;
    int v2 = blockIdx.x * 64 + dd2;
    if (v2 >= n) return;
    float o[8];
#pragma unroll
    for (int c = 0; c < 8; ++c) o[c] = 0.f;
#pragma unroll 8
    for (int k = 0; k < 32; ++k) {
        float skv = svec[dd2][k];
        const float* wr = &wc[k][oo * 8];
        o[0] = fmaf(skv, wr[0], o[0]);
        o[1] = fmaf(skv, wr[1], o[1]);
        o[2] = fmaf(skv, wr[2], o[2]);
        o[3] = fmaf(skv, wr[3], o[3]);
        o[4] = fmaf(skv, wr[4], o[4]);
        o[5] = fmaf(skv, wr[5], o[5]);
        o[6] = fmaf(skv, wr[6], o[6]);
        o[7] = fmaf(skv, wr[7], o[7]);
    }
    float* dst;
    const float* bsrc;
    if (oo < 2) { dst = out + (size_t)v2 * OUT_CH + oo * 8;                       bsrc = bmu + oo * 8; }
    else        { dst = out + (size_t)N_NODES * OUT_CH + (size_t)v2 * OUT_CH + (oo - 2) * 8; bsrc = blv + (oo - 2) * 8; }
    float4 b0 = *reinterpret_cast<const float4*>(bsrc);
    float4 b1v = *reinterpret_cast<const float4*>(bsrc + 4);
    *reinterpret_cast<float4*>(dst)     = make_float4(o[0] + b0.x, o[1] + b0.y, o[2] + b0.z, o[3] + b0.w);
    *reinterpret_cast<float4*>(dst + 4) = make_float4(o[4] + b1v.x, o[5] + b1v.y, o[6] + b1v.z, o[7] + b1v.w);
}

// ---------------- launch ----------------

extern "C" void kernel_launch(void* const* d_in, const int* in_sizes, int n_in,
                              void* d_out, int out_size, void* d_ws, size_t ws_size,
                              hipStream_t stream) {
    const float* x   = (const float*)d_in[0];
    const int*   ei  = (const int*)d_in[1];
    const float* W1  = (const float*)d_in[2];
    const float* b1  = (const float*)d_in[3];
    const float* Wmu = (const float*)d_in[4];
    const float* bmu = (const float*)d_in[5];
    const float* Wlv = (const float*)d_in[6];
    const float* blv = (const float*)d_in[7];
    float* out = (float*)d_out;

    const int* row = ei;            // edge_index[0]
    const int* col = ei + E_EDGES;  // edge_index[1]

    char* w = (char*)d_ws;
    int*   bcnt   = (int*)w;  w += 1024;
    int*   bstart = (int*)w;  w += 1024;
    uint4* W1f    = (uint4*)w; w += 16384;                         // 1024 * 16B fragments
    int*   ghist  = (int*)w;  w += (size_t)PB * B_BUCKETS * 4;     // 1 MB
    int*   deg    = (int*)w;  w += (size_t)N_NODES * 4;
    float* dis    = (float*)w; w += (size_t)N_NODES * 4;
    int*   start  = (int*)w;  w += (size_t)N_NODES * 4;
    int*   srow   = (int*)w;  w += (size_t)(E_EDGES + 16 + B_BUCKETS * PADSTRIDE) * 4;  // padded CSR
    u16*   h0sh   = (u16*)w;  w += (size_t)(N_NODES + 1) * HID * 2;  // +1 zero row
    u16*   hsh    = (u16*)w;  w += (size_t)(N_NODES + 1) * HID * 2;
    unsigned* psrc = (unsigned*)w; w += (size_t)E_EDGES * 4;

    const int TB = 256;
    k_pre<<<PB + 1, TB, 0, stream>>>(col, ghist, W1, W1f, E_EDGES);
    k_scan<<<B_BUCKETS, 1024, 0, stream>>>(ghist, bcnt);
    k_bscan<<<1, 256, 0, stream>>>(bcnt, bstart, h0sh, hsh);
    k_place<<<PB + GEMM_BLOCKS, TB, 0, stream>>>(row, col, bstart, ghist, bcnt, psrc,
                                                 x, W1f, h0sh, N_NODES);
    k_bsort<<<B_BUCKETS, 512, 0, stream>>>(psrc, bstart, srow, deg, start, dis, h0sh);
    k_agg1<<<(N_NODES + 63) / 64, TB, 0, stream>>>(h0sh, srow, start, deg, dis, b1, hsh, N_NODES);
    k_agg2<<<(N_NODES + 63) / 64, TB, 0, stream>>>(hsh, srow, start, deg, dis,
                                                   Wmu, Wlv, bmu, blv, out, N_NODES);
}